// Round 1
// baseline (3844.585 us; speedup 1.0000x reference)
//
#include <hip/hip_runtime.h>
#include <math.h>

// DiffRankNet: HGNN forward on MI355X.
// Pipeline per feature set: rownorm -> gram (XX^T, sym) -> top15/row ->
// degrees -> CSR transpose adjacency -> t1=X@W1 -> sparse A-apply ->
// relu -> t2@W2 -> sparse A-apply -> global mean-sum.
// out = [sigmoid(y0-y1), y0, y1]

#define NN   4096
#define CC   1024
#define HIDN 512
#define FEATN 128
#define NE   12288   // 3*NN hyperedges
#define KTOT 30      // 5+10+15 nnz per node-column group
#define KMAX 15

// ---------------- row squared norms ----------------
__global__ __launch_bounds__(256) void k_rownorm(const float* __restrict__ X,
                                                 float* __restrict__ nrm) {
    __shared__ float s[256];
    int i = blockIdx.x, t = threadIdx.x;
    const float* row = X + (size_t)i * CC;
    float acc = 0.f;
#pragma unroll
    for (int j = 0; j < CC / 256; ++j) { float v = row[t + 256 * j]; acc += v * v; }
    s[t] = acc; __syncthreads();
    for (int d = 128; d > 0; d >>= 1) { if (t < d) s[t] += s[t + d]; __syncthreads(); }
    if (t == 0) nrm[i] = s[0];
}

// ---------------- Gram: G = X X^T, 128x128 tiles, symmetric ----------------
__global__ __launch_bounds__(256) void k_gram(const float* __restrict__ X,
                                              float* __restrict__ G) {
    int bi = blockIdx.y, bj = blockIdx.x;
    if (bj < bi) return;  // symmetry: compute upper blocks, write both
    __shared__ float As[16][136];
    __shared__ float Bs[16][136];
    int t = threadIdx.x;
    int g = t >> 4, h = t & 15;
    int r0 = g * 8, c0 = h * 8;
    float acc[8][8] = {};
    const int rowA = bi * 128, rowB = bj * 128;
    for (int k0 = 0; k0 < CC; k0 += 16) {
#pragma unroll
        for (int l = 0; l < 2; ++l) {
            int lin = t + l * 256;          // 0..511
            int r = lin >> 2;               // 0..127
            int kc = (lin & 3) * 4;         // 0,4,8,12
            float4 a = *reinterpret_cast<const float4*>(&X[(size_t)(rowA + r) * CC + k0 + kc]);
            As[kc + 0][r] = a.x; As[kc + 1][r] = a.y; As[kc + 2][r] = a.z; As[kc + 3][r] = a.w;
            float4 b = *reinterpret_cast<const float4*>(&X[(size_t)(rowB + r) * CC + k0 + kc]);
            Bs[kc + 0][r] = b.x; Bs[kc + 1][r] = b.y; Bs[kc + 2][r] = b.z; Bs[kc + 3][r] = b.w;
        }
        __syncthreads();
#pragma unroll
        for (int kk = 0; kk < 16; ++kk) {
            float a[8], b[8];
#pragma unroll
            for (int u = 0; u < 8; ++u) a[u] = As[kk][r0 + u];
#pragma unroll
            for (int v = 0; v < 8; ++v) b[v] = Bs[kk][c0 + v];
#pragma unroll
            for (int u = 0; u < 8; ++u)
#pragma unroll
                for (int v = 0; v < 8; ++v)
                    acc[u][v] += a[u] * b[v];
        }
        __syncthreads();
    }
    // write (bi,bj) block
#pragma unroll
    for (int u = 0; u < 8; ++u) {
        int r = rowA + r0 + u;
        float4* p4 = reinterpret_cast<float4*>(&G[(size_t)r * NN + rowB + c0]);
        p4[0] = make_float4(acc[u][0], acc[u][1], acc[u][2], acc[u][3]);
        p4[1] = make_float4(acc[u][4], acc[u][5], acc[u][6], acc[u][7]);
    }
    if (bi != bj) {
        // transposed block (bj,bi)
#pragma unroll
        for (int v = 0; v < 8; ++v) {
            int r = rowB + c0 + v;
            float4* p4 = reinterpret_cast<float4*>(&G[(size_t)r * NN + rowA + r0]);
            p4[0] = make_float4(acc[0][v], acc[1][v], acc[2][v], acc[3][v]);
            p4[1] = make_float4(acc[4][v], acc[5][v], acc[6][v], acc[7][v]);
        }
    }
}

// ---------------- top-15 smallest distances per row ----------------
__global__ __launch_bounds__(256) void k_topk(const float* __restrict__ G,
                                              const float* __restrict__ nrm,
                                              int* __restrict__ idx_out) {
    __shared__ float d2[NN];     // 16 KB
    __shared__ float bv[256];
    __shared__ int   bidx[256];
    int e = blockIdx.x, t = threadIdx.x;
    float ne = nrm[e];
    const float* Grow = G + (size_t)e * NN;
    for (int i = t; i < NN; i += 256) {
        float v = ne + nrm[i] - 2.0f * Grow[i];
        d2[i] = fmaxf(v, 0.0f);
    }
    __syncthreads();
    for (int r = 0; r < KMAX; ++r) {
        float best = INFINITY; int bi_ = NN;
        for (int i = t; i < NN; i += 256) {
            float v = d2[i];
            if (v < best) { best = v; bi_ = i; }  // increasing i: strict < keeps lowest idx on tie
        }
        bv[t] = best; bidx[t] = bi_;
        __syncthreads();
        for (int s = 128; s > 0; s >>= 1) {
            if (t < s) {
                float v2 = bv[t + s]; int i2 = bidx[t + s];
                if (v2 < bv[t] || (v2 == bv[t] && i2 < bidx[t])) { bv[t] = v2; bidx[t] = i2; }
            }
            __syncthreads();
        }
        if (t == 0) {
            idx_out[e * 16 + r] = bidx[0];
            d2[bidx[0]] = INFINITY;
        }
        __syncthreads();
    }
}

// ---------------- node degrees (across all 3 k-blocks) ----------------
__device__ __forceinline__ void decode_pair(int p, int& e, int& b, int& j) {
    e = p / KTOT;
    int q = p - e * KTOT;
    if (q < 5)       { b = 0; j = q; }
    else if (q < 15) { b = 1; j = q - 5; }
    else             { b = 2; j = q - 15; }
}

__global__ __launch_bounds__(256) void k_count(const int* __restrict__ idx, int* __restrict__ Dv) {
    int p = blockIdx.x * 256 + threadIdx.x;  // < NN*KTOT
    int e, b, j; decode_pair(p, e, b, j);
    (void)b;
    atomicAdd(&Dv[idx[e * 16 + j]], 1);
}

__global__ __launch_bounds__(256) void k_dv(const int* __restrict__ Dv, float* __restrict__ dvv) {
    int i = blockIdx.x * 256 + threadIdx.x;
    int d = Dv[i];
    dvv[i] = d > 0 ? 1.0f / sqrtf((float)d) : 0.0f;
}

// ---------------- exclusive scan of degrees (single block) ----------------
__global__ __launch_bounds__(1024) void k_scan(const int* __restrict__ Dv,
                                               int* __restrict__ offs,
                                               int* __restrict__ cur) {
    __shared__ int s[1024];
    int t = threadIdx.x;
    int v[4]; int sum = 0;
#pragma unroll
    for (int j = 0; j < 4; ++j) { v[j] = Dv[t * 4 + j]; sum += v[j]; }
    s[t] = sum; __syncthreads();
    for (int d = 1; d < 1024; d <<= 1) {
        int add = (t >= d) ? s[t - d] : 0;
        __syncthreads();
        s[t] += add;
        __syncthreads();
    }
    int run = s[t] - sum;  // exclusive
#pragma unroll
    for (int j = 0; j < 4; ++j) { offs[t * 4 + j] = run; cur[t * 4 + j] = run; run += v[j]; }
    if (t == 1023) offs[NN] = run;
}

__global__ __launch_bounds__(256) void k_fill(const int* __restrict__ idx,
                                              int* __restrict__ cur,
                                              int* __restrict__ adj) {
    int p = blockIdx.x * 256 + threadIdx.x;
    int e, b, j; decode_pair(p, e, b, j);
    int i = idx[e * 16 + j];
    int eg = b * NN + e;
    int pos = atomicAdd(&cur[i], 1);
    adj[pos] = eg;
}

// ---------------- generic tiled GEMM: C = act(A) @ B ----------------
template <bool RELU>
__global__ __launch_bounds__(256) void k_gemm(const float* __restrict__ A,
                                              const float* __restrict__ B,
                                              float* __restrict__ Cm,
                                              int M, int K, int Nc) {
    __shared__ float As[16][68];
    __shared__ float Bs[16][68];
    int bi = blockIdx.y, bj = blockIdx.x, t = threadIdx.x;
    int g = t >> 4, h = t & 15;
    int r0 = g * 4, c0 = h * 4;
    float acc[4][4] = {};
    for (int k0 = 0; k0 < K; k0 += 16) {
        {
            int r = t >> 2;            // 0..63
            int kc = (t & 3) * 4;
            float4 a = *reinterpret_cast<const float4*>(&A[(size_t)(bi * 64 + r) * K + k0 + kc]);
            if (RELU) { a.x = fmaxf(a.x, 0.f); a.y = fmaxf(a.y, 0.f); a.z = fmaxf(a.z, 0.f); a.w = fmaxf(a.w, 0.f); }
            As[kc + 0][r] = a.x; As[kc + 1][r] = a.y; As[kc + 2][r] = a.z; As[kc + 3][r] = a.w;
        }
        {
            int kr = t >> 4;           // 0..15
            int c = (t & 15) * 4;
            float4 b = *reinterpret_cast<const float4*>(&B[(size_t)(k0 + kr) * Nc + bj * 64 + c]);
            *reinterpret_cast<float4*>(&Bs[kr][c]) = b;
        }
        __syncthreads();
#pragma unroll
        for (int kk = 0; kk < 16; ++kk) {
            float a[4], b[4];
#pragma unroll
            for (int u = 0; u < 4; ++u) a[u] = As[kk][r0 + u];
#pragma unroll
            for (int v = 0; v < 4; ++v) b[v] = Bs[kk][c0 + v];
#pragma unroll
            for (int u = 0; u < 4; ++u)
#pragma unroll
                for (int v = 0; v < 4; ++v)
                    acc[u][v] += a[u] * b[v];
        }
        __syncthreads();
    }
#pragma unroll
    for (int u = 0; u < 4; ++u) {
        float4* p4 = reinterpret_cast<float4*>(&Cm[(size_t)(bi * 64 + r0 + u) * Nc + bj * 64 + c0]);
        *p4 = make_float4(acc[u][0], acc[u][1], acc[u][2], acc[u][3]);
    }
}

// ---------------- hyperedge gather: m[e,:] = de * sum_{i in S_e} dv_i * t[i,:] ----------------
template <int F>
__global__ __launch_bounds__(256) void k_edge(const int* __restrict__ idx,
                                              const float* __restrict__ dvv,
                                              const float* __restrict__ tin,
                                              float* __restrict__ m) {
    int p = blockIdx.x * 256 + threadIdx.x;
    int c = p & (F - 1);
    int eg = p / F;
    int b = eg >> 12;          // NN = 4096
    int e = eg & (NN - 1);
    int kb = (b == 0) ? 5 : (b == 1) ? 10 : 15;
    float de = 1.0f / (float)kb;
    float acc = 0.f;
    for (int j = 0; j < kb; ++j) {
        int i = idx[e * 16 + j];
        acc += dvv[i] * tin[(size_t)i * F + c];
    }
    m[(size_t)eg * F + c] = de * acc;
}

// ---------------- node gather: u[i,:] = dv_i * sum_{e in adj(i)} m[e,:] ----------------
template <int F>
__global__ __launch_bounds__(256) void k_node(const int* __restrict__ offs,
                                              const int* __restrict__ adj,
                                              const float* __restrict__ dvv,
                                              const float* __restrict__ m,
                                              float* __restrict__ u) {
    int p = blockIdx.x * 256 + threadIdx.x;
    int c = p & (F - 1);
    int i = p / F;
    int q0 = offs[i], q1 = offs[i + 1];
    float acc = 0.f;
    for (int q = q0; q < q1; ++q) {
        acc += m[(size_t)adj[q] * F + c];
    }
    u[(size_t)i * F + c] = dvv[i] * acc;
}

// ---------------- reductions ----------------
__global__ __launch_bounds__(256) void k_rpart(const float* __restrict__ u2, float* __restrict__ part) {
    __shared__ float s[256];
    float acc = 0.f;
    for (int i = blockIdx.x * 256 + threadIdx.x; i < NN * FEATN; i += 256 * 256) acc += u2[i];
    s[threadIdx.x] = acc; __syncthreads();
    for (int d = 128; d > 0; d >>= 1) { if (threadIdx.x < d) s[threadIdx.x] += s[threadIdx.x + d]; __syncthreads(); }
    if (threadIdx.x == 0) part[blockIdx.x] = s[0];
}

__global__ __launch_bounds__(256) void k_rfinal(const float* __restrict__ part, float* __restrict__ ys, int slot) {
    __shared__ float s[256];
    s[threadIdx.x] = part[threadIdx.x]; __syncthreads();
    for (int d = 128; d > 0; d >>= 1) { if (threadIdx.x < d) s[threadIdx.x] += s[threadIdx.x + d]; __syncthreads(); }
    if (threadIdx.x == 0) ys[slot] = s[0] / (float)NN;
}

__global__ void k_fin(const float* __restrict__ ys, float* __restrict__ out) {
    float y0 = ys[0], y1 = ys[1];
    out[0] = 1.0f / (1.0f + expf(-(y0 - y1)));
    out[1] = y0;
    out[2] = y1;
}

// ---------------- launch ----------------
extern "C" void kernel_launch(void* const* d_in, const int* in_sizes, int n_in,
                              void* d_out, int out_size, void* d_ws, size_t ws_size,
                              hipStream_t stream) {
    const float* fts[2] = { (const float*)d_in[0], (const float*)d_in[1] };
    const float* W1 = (const float*)d_in[2];
    const float* W2 = (const float*)d_in[3];
    float* out = (float*)d_out;

    char* p = (char*)d_ws;
    auto alloc = [&](size_t b) { char* r = p; p += (b + 255) & ~(size_t)255; return r; };
    float* G    = (float*)alloc((size_t)NN * NN * 4);        // 64 MB
    float* nrm  = (float*)alloc((size_t)NN * 4);
    int*   idx  = (int*)  alloc((size_t)NN * 16 * 4);
    int*   Dv   = (int*)  alloc((size_t)NN * 4);
    float* dvv  = (float*)alloc((size_t)NN * 4);
    int*   offs = (int*)  alloc((size_t)(NN + 1) * 4);
    int*   cur  = (int*)  alloc((size_t)NN * 4);
    int*   adj  = (int*)  alloc((size_t)NN * KTOT * 4);
    float* t1   = (float*)alloc((size_t)NN * HIDN * 4);
    float* u1   = (float*)alloc((size_t)NN * HIDN * 4);
    float* t2   = (float*)alloc((size_t)NN * FEATN * 4);
    float* u2   = (float*)alloc((size_t)NN * FEATN * 4);
    float* m    = (float*)alloc((size_t)NE * HIDN * 4);      // 25 MB (reused for F=128)
    float* part = (float*)alloc(256 * 4);
    float* ys   = (float*)alloc(2 * 4);

    for (int s = 0; s < 2; ++s) {
        const float* X = fts[s];
        k_rownorm<<<NN, 256, 0, stream>>>(X, nrm);
        k_gram<<<dim3(NN / 128, NN / 128), 256, 0, stream>>>(X, G);
        k_topk<<<NN, 256, 0, stream>>>(G, nrm, idx);
        hipMemsetAsync(Dv, 0, NN * 4, stream);
        k_count<<<NN * KTOT / 256, 256, 0, stream>>>(idx, Dv);
        k_dv<<<NN / 256, 256, 0, stream>>>(Dv, dvv);
        k_scan<<<1, 1024, 0, stream>>>(Dv, offs, cur);
        k_fill<<<NN * KTOT / 256, 256, 0, stream>>>(idx, cur, adj);
        // conv1: t1 = X @ W1 ; u1 = A t1
        k_gemm<false><<<dim3(HIDN / 64, NN / 64), 256, 0, stream>>>(X, W1, t1, NN, CC, HIDN);
        k_edge<HIDN><<<NE * HIDN / 256, 256, 0, stream>>>(idx, dvv, t1, m);
        k_node<HIDN><<<NN * HIDN / 256, 256, 0, stream>>>(offs, adj, dvv, m, u1);
        // conv2: t2 = relu(u1) @ W2 ; u2 = A t2
        k_gemm<true><<<dim3(FEATN / 64, NN / 64), 256, 0, stream>>>(u1, W2, t2, NN, HIDN, FEATN);
        k_edge<FEATN><<<NE * FEATN / 256, 256, 0, stream>>>(idx, dvv, t2, m);
        k_node<FEATN><<<NN * FEATN / 256, 256, 0, stream>>>(offs, adj, dvv, m, u2);
        // y_s = mean over nodes, summed over features
        k_rpart<<<256, 256, 0, stream>>>(u2, part);
        k_rfinal<<<1, 256, 0, stream>>>(part, ys, s);
    }
    k_fin<<<1, 1, 0, stream>>>(ys, out);
}

// Round 2
// 1998.236 us; speedup vs baseline: 1.9240x; 1.9240x over previous
//
#include <hip/hip_runtime.h>
#include <math.h>

// DiffRankNet: HGNN forward on MI355X.
// R1: float4 + ILP-unrolled sparse gathers (k_edge/k_node); dv folded into GEMM epilogue.
// out = [sigmoid(y0-y1), y0, y1]

#define NN   4096
#define CC   1024
#define HIDN 512
#define FEATN 128
#define NE   12288   // 3*NN hyperedges
#define KTOT 30      // 5+10+15 nnz per node-column group
#define KMAX 15

// ---------------- row squared norms ----------------
__global__ __launch_bounds__(256) void k_rownorm(const float* __restrict__ X,
                                                 float* __restrict__ nrm) {
    __shared__ float s[256];
    int i = blockIdx.x, t = threadIdx.x;
    const float* row = X + (size_t)i * CC;
    float acc = 0.f;
#pragma unroll
    for (int j = 0; j < CC / 256; ++j) { float v = row[t + 256 * j]; acc += v * v; }
    s[t] = acc; __syncthreads();
    for (int d = 128; d > 0; d >>= 1) { if (t < d) s[t] += s[t + d]; __syncthreads(); }
    if (t == 0) nrm[i] = s[0];
}

// ---------------- Gram: G = X X^T, 128x128 tiles, symmetric ----------------
__global__ __launch_bounds__(256) void k_gram(const float* __restrict__ X,
                                              float* __restrict__ G) {
    int bi = blockIdx.y, bj = blockIdx.x;
    if (bj < bi) return;  // symmetry: compute upper blocks, write both
    __shared__ float As[16][136];
    __shared__ float Bs[16][136];
    int t = threadIdx.x;
    int g = t >> 4, h = t & 15;
    int r0 = g * 8, c0 = h * 8;
    float acc[8][8] = {};
    const int rowA = bi * 128, rowB = bj * 128;
    for (int k0 = 0; k0 < CC; k0 += 16) {
#pragma unroll
        for (int l = 0; l < 2; ++l) {
            int lin = t + l * 256;          // 0..511
            int r = lin >> 2;               // 0..127
            int kc = (lin & 3) * 4;         // 0,4,8,12
            float4 a = *reinterpret_cast<const float4*>(&X[(size_t)(rowA + r) * CC + k0 + kc]);
            As[kc + 0][r] = a.x; As[kc + 1][r] = a.y; As[kc + 2][r] = a.z; As[kc + 3][r] = a.w;
            float4 b = *reinterpret_cast<const float4*>(&X[(size_t)(rowB + r) * CC + k0 + kc]);
            Bs[kc + 0][r] = b.x; Bs[kc + 1][r] = b.y; Bs[kc + 2][r] = b.z; Bs[kc + 3][r] = b.w;
        }
        __syncthreads();
#pragma unroll
        for (int kk = 0; kk < 16; ++kk) {
            float a[8], b[8];
#pragma unroll
            for (int u = 0; u < 8; ++u) a[u] = As[kk][r0 + u];
#pragma unroll
            for (int v = 0; v < 8; ++v) b[v] = Bs[kk][c0 + v];
#pragma unroll
            for (int u = 0; u < 8; ++u)
#pragma unroll
                for (int v = 0; v < 8; ++v)
                    acc[u][v] += a[u] * b[v];
        }
        __syncthreads();
    }
#pragma unroll
    for (int u = 0; u < 8; ++u) {
        int r = rowA + r0 + u;
        float4* p4 = reinterpret_cast<float4*>(&G[(size_t)r * NN + rowB + c0]);
        p4[0] = make_float4(acc[u][0], acc[u][1], acc[u][2], acc[u][3]);
        p4[1] = make_float4(acc[u][4], acc[u][5], acc[u][6], acc[u][7]);
    }
    if (bi != bj) {
#pragma unroll
        for (int v = 0; v < 8; ++v) {
            int r = rowB + c0 + v;
            float4* p4 = reinterpret_cast<float4*>(&G[(size_t)r * NN + rowA + r0]);
            p4[0] = make_float4(acc[0][v], acc[1][v], acc[2][v], acc[3][v]);
            p4[1] = make_float4(acc[4][v], acc[5][v], acc[6][v], acc[7][v]);
        }
    }
}

// ---------------- top-15 smallest distances per row ----------------
__global__ __launch_bounds__(256) void k_topk(const float* __restrict__ G,
                                              const float* __restrict__ nrm,
                                              int* __restrict__ idx_out) {
    __shared__ float d2[NN];     // 16 KB
    __shared__ float bv[256];
    __shared__ int   bidx[256];
    int e = blockIdx.x, t = threadIdx.x;
    float ne = nrm[e];
    const float* Grow = G + (size_t)e * NN;
    for (int i = t; i < NN; i += 256) {
        float v = ne + nrm[i] - 2.0f * Grow[i];
        d2[i] = fmaxf(v, 0.0f);
    }
    __syncthreads();
    for (int r = 0; r < KMAX; ++r) {
        float best = INFINITY; int bi_ = NN;
        for (int i = t; i < NN; i += 256) {
            float v = d2[i];
            if (v < best) { best = v; bi_ = i; }  // increasing i: strict < keeps lowest idx on tie
        }
        bv[t] = best; bidx[t] = bi_;
        __syncthreads();
        for (int s = 128; s > 0; s >>= 1) {
            if (t < s) {
                float v2 = bv[t + s]; int i2 = bidx[t + s];
                if (v2 < bv[t] || (v2 == bv[t] && i2 < bidx[t])) { bv[t] = v2; bidx[t] = i2; }
            }
            __syncthreads();
        }
        if (t == 0) {
            idx_out[e * 16 + r] = bidx[0];
            d2[bidx[0]] = INFINITY;
        }
        __syncthreads();
    }
}

// ---------------- node degrees (across all 3 k-blocks) ----------------
__device__ __forceinline__ void decode_pair(int p, int& e, int& b, int& j) {
    e = p / KTOT;
    int q = p - e * KTOT;
    if (q < 5)       { b = 0; j = q; }
    else if (q < 15) { b = 1; j = q - 5; }
    else             { b = 2; j = q - 15; }
}

__global__ __launch_bounds__(256) void k_count(const int* __restrict__ idx, int* __restrict__ Dv) {
    int p = blockIdx.x * 256 + threadIdx.x;  // < NN*KTOT
    int e, b, j; decode_pair(p, e, b, j);
    (void)b;
    atomicAdd(&Dv[idx[e * 16 + j]], 1);
}

__global__ __launch_bounds__(256) void k_dv(const int* __restrict__ Dv, float* __restrict__ dvv) {
    int i = blockIdx.x * 256 + threadIdx.x;
    int d = Dv[i];
    dvv[i] = d > 0 ? 1.0f / sqrtf((float)d) : 0.0f;
}

// ---------------- exclusive scan of degrees (single block) ----------------
__global__ __launch_bounds__(1024) void k_scan(const int* __restrict__ Dv,
                                               int* __restrict__ offs,
                                               int* __restrict__ cur) {
    __shared__ int s[1024];
    int t = threadIdx.x;
    int v[4]; int sum = 0;
#pragma unroll
    for (int j = 0; j < 4; ++j) { v[j] = Dv[t * 4 + j]; sum += v[j]; }
    s[t] = sum; __syncthreads();
    for (int d = 1; d < 1024; d <<= 1) {
        int add = (t >= d) ? s[t - d] : 0;
        __syncthreads();
        s[t] += add;
        __syncthreads();
    }
    int run = s[t] - sum;  // exclusive
#pragma unroll
    for (int j = 0; j < 4; ++j) { offs[t * 4 + j] = run; cur[t * 4 + j] = run; run += v[j]; }
    if (t == 1023) offs[NN] = run;
}

__global__ __launch_bounds__(256) void k_fill(const int* __restrict__ idx,
                                              int* __restrict__ cur,
                                              int* __restrict__ adj) {
    int p = blockIdx.x * 256 + threadIdx.x;
    int e, b, j; decode_pair(p, e, b, j);
    int i = idx[e * 16 + j];
    int eg = b * NN + e;
    int pos = atomicAdd(&cur[i], 1);
    adj[pos] = eg;
}

// ---------------- generic tiled GEMM: C = rowscale? * (act(A) @ B) ----------------
template <bool RELU, bool SCALE>
__global__ __launch_bounds__(256) void k_gemm(const float* __restrict__ A,
                                              const float* __restrict__ B,
                                              const float* __restrict__ rowscale,
                                              float* __restrict__ Cm,
                                              int M, int K, int Nc) {
    __shared__ float As[16][68];
    __shared__ float Bs[16][68];
    int bi = blockIdx.y, bj = blockIdx.x, t = threadIdx.x;
    int g = t >> 4, h = t & 15;
    int r0 = g * 4, c0 = h * 4;
    float acc[4][4] = {};
    for (int k0 = 0; k0 < K; k0 += 16) {
        {
            int r = t >> 2;            // 0..63
            int kc = (t & 3) * 4;
            float4 a = *reinterpret_cast<const float4*>(&A[(size_t)(bi * 64 + r) * K + k0 + kc]);
            if (RELU) { a.x = fmaxf(a.x, 0.f); a.y = fmaxf(a.y, 0.f); a.z = fmaxf(a.z, 0.f); a.w = fmaxf(a.w, 0.f); }
            As[kc + 0][r] = a.x; As[kc + 1][r] = a.y; As[kc + 2][r] = a.z; As[kc + 3][r] = a.w;
        }
        {
            int kr = t >> 4;           // 0..15
            int c = (t & 15) * 4;
            float4 b = *reinterpret_cast<const float4*>(&B[(size_t)(k0 + kr) * Nc + bj * 64 + c]);
            *reinterpret_cast<float4*>(&Bs[kr][c]) = b;
        }
        __syncthreads();
#pragma unroll
        for (int kk = 0; kk < 16; ++kk) {
            float a[4], b[4];
#pragma unroll
            for (int u = 0; u < 4; ++u) a[u] = As[kk][r0 + u];
#pragma unroll
            for (int v = 0; v < 4; ++v) b[v] = Bs[kk][c0 + v];
#pragma unroll
            for (int u = 0; u < 4; ++u)
#pragma unroll
                for (int v = 0; v < 4; ++v)
                    acc[u][v] += a[u] * b[v];
        }
        __syncthreads();
    }
#pragma unroll
    for (int u = 0; u < 4; ++u) {
        int r = bi * 64 + r0 + u;
        float sc = SCALE ? rowscale[r] : 1.0f;
        float4* p4 = reinterpret_cast<float4*>(&Cm[(size_t)r * Nc + bj * 64 + c0]);
        *p4 = make_float4(acc[u][0] * sc, acc[u][1] * sc, acc[u][2] * sc, acc[u][3] * sc);
    }
}

// ---------------- hyperedge gather: m[EB+e,:] = (1/KB) * sum_j ts[idx[e][j],:] ----------------
// ts is already row-scaled by dv. KB compile-time -> fully unrolled, 15 independent load chains.
template <int F, int KB, int JOFF, int EB>
__global__ __launch_bounds__(256) void k_edge2(const int* __restrict__ idx,
                                               const float* __restrict__ ts,
                                               float* __restrict__ m) {
    constexpr int CPE = F / 4;                  // float4 lanes per edge
    constexpr int LG = (F == 512) ? 7 : 5;
    int p = blockIdx.x * 256 + threadIdx.x;     // NN * CPE threads
    int e = p >> LG;
    int c4 = (p & (CPE - 1)) * 4;
    const int* row = idx + e * 16 + JOFF;
    float4 acc = make_float4(0.f, 0.f, 0.f, 0.f);
#pragma unroll
    for (int j = 0; j < KB; ++j) {
        int i = row[j];
        float4 v = *reinterpret_cast<const float4*>(&ts[(size_t)i * F + c4]);
        acc.x += v.x; acc.y += v.y; acc.z += v.z; acc.w += v.w;
    }
    constexpr float de = 1.0f / (float)KB;
    float4* o = reinterpret_cast<float4*>(&m[(size_t)(EB + e) * F + c4]);
    *o = make_float4(acc.x * de, acc.y * de, acc.z * de, acc.w * de);
}

// ---------------- node gather: u[i,:] = dv_i * sum_{e in adj(i)} m[e,:] ----------------
// float4 per thread, 4-way unrolled -> 8 independent loads in flight.
template <int F>
__global__ __launch_bounds__(256) void k_node2(const int* __restrict__ offs,
                                               const int* __restrict__ adj,
                                               const float* __restrict__ dvv,
                                               const float* __restrict__ m,
                                               float* __restrict__ u) {
    constexpr int CPN = F / 4;
    constexpr int LG = (F == 512) ? 7 : 5;
    int p = blockIdx.x * 256 + threadIdx.x;     // NN * CPN threads
    int i = p >> LG;
    int c4 = (p & (CPN - 1)) * 4;
    int q0 = offs[i], q1 = offs[i + 1];
    float4 acc = make_float4(0.f, 0.f, 0.f, 0.f);
    int q = q0;
    for (; q + 4 <= q1; q += 4) {
        int e0 = adj[q], e1 = adj[q + 1], e2 = adj[q + 2], e3 = adj[q + 3];
        float4 v0 = *reinterpret_cast<const float4*>(&m[(size_t)e0 * F + c4]);
        float4 v1 = *reinterpret_cast<const float4*>(&m[(size_t)e1 * F + c4]);
        float4 v2 = *reinterpret_cast<const float4*>(&m[(size_t)e2 * F + c4]);
        float4 v3 = *reinterpret_cast<const float4*>(&m[(size_t)e3 * F + c4]);
        acc.x += v0.x + v1.x + v2.x + v3.x;
        acc.y += v0.y + v1.y + v2.y + v3.y;
        acc.z += v0.z + v1.z + v2.z + v3.z;
        acc.w += v0.w + v1.w + v2.w + v3.w;
    }
    for (; q < q1; ++q) {
        float4 v = *reinterpret_cast<const float4*>(&m[(size_t)adj[q] * F + c4]);
        acc.x += v.x; acc.y += v.y; acc.z += v.z; acc.w += v.w;
    }
    float dv = dvv[i];
    float4* o = reinterpret_cast<float4*>(&u[(size_t)i * F + c4]);
    *o = make_float4(acc.x * dv, acc.y * dv, acc.z * dv, acc.w * dv);
}

// ---------------- reductions ----------------
__global__ __launch_bounds__(256) void k_rpart(const float* __restrict__ u2, float* __restrict__ part) {
    __shared__ float s[256];
    float acc = 0.f;
    for (int i = blockIdx.x * 256 + threadIdx.x; i < NN * FEATN; i += 256 * 256) acc += u2[i];
    s[threadIdx.x] = acc; __syncthreads();
    for (int d = 128; d > 0; d >>= 1) { if (threadIdx.x < d) s[threadIdx.x] += s[threadIdx.x + d]; __syncthreads(); }
    if (threadIdx.x == 0) part[blockIdx.x] = s[0];
}

__global__ __launch_bounds__(256) void k_rfinal(const float* __restrict__ part, float* __restrict__ ys, int slot) {
    __shared__ float s[256];
    s[threadIdx.x] = part[threadIdx.x]; __syncthreads();
    for (int d = 128; d > 0; d >>= 1) { if (threadIdx.x < d) s[threadIdx.x] += s[threadIdx.x + d]; __syncthreads(); }
    if (threadIdx.x == 0) ys[slot] = s[0] / (float)NN;
}

__global__ void k_fin(const float* __restrict__ ys, float* __restrict__ out) {
    float y0 = ys[0], y1 = ys[1];
    out[0] = 1.0f / (1.0f + expf(-(y0 - y1)));
    out[1] = y0;
    out[2] = y1;
}

// ---------------- launch ----------------
extern "C" void kernel_launch(void* const* d_in, const int* in_sizes, int n_in,
                              void* d_out, int out_size, void* d_ws, size_t ws_size,
                              hipStream_t stream) {
    const float* fts[2] = { (const float*)d_in[0], (const float*)d_in[1] };
    const float* W1 = (const float*)d_in[2];
    const float* W2 = (const float*)d_in[3];
    float* out = (float*)d_out;

    char* p = (char*)d_ws;
    auto alloc = [&](size_t b) { char* r = p; p += (b + 255) & ~(size_t)255; return r; };
    float* G    = (float*)alloc((size_t)NN * NN * 4);        // 64 MB
    float* nrm  = (float*)alloc((size_t)NN * 4);
    int*   idx  = (int*)  alloc((size_t)NN * 16 * 4);
    int*   Dv   = (int*)  alloc((size_t)NN * 4);
    float* dvv  = (float*)alloc((size_t)NN * 4);
    int*   offs = (int*)  alloc((size_t)(NN + 1) * 4);
    int*   cur  = (int*)  alloc((size_t)NN * 4);
    int*   adj  = (int*)  alloc((size_t)NN * KTOT * 4);
    float* t1   = (float*)alloc((size_t)NN * HIDN * 4);      // dv-scaled X@W1
    float* u1   = (float*)alloc((size_t)NN * HIDN * 4);
    float* t2   = (float*)alloc((size_t)NN * FEATN * 4);     // dv-scaled relu(u1)@W2
    float* u2   = (float*)alloc((size_t)NN * FEATN * 4);
    float* m    = (float*)alloc((size_t)NE * HIDN * 4);      // 25 MB (reused for F=128)
    float* part = (float*)alloc(256 * 4);
    float* ys   = (float*)alloc(2 * 4);

    for (int s = 0; s < 2; ++s) {
        const float* X = fts[s];
        k_rownorm<<<NN, 256, 0, stream>>>(X, nrm);
        k_gram<<<dim3(NN / 128, NN / 128), 256, 0, stream>>>(X, G);
        k_topk<<<NN, 256, 0, stream>>>(G, nrm, idx);
        hipMemsetAsync(Dv, 0, NN * 4, stream);
        k_count<<<NN * KTOT / 256, 256, 0, stream>>>(idx, Dv);
        k_dv<<<NN / 256, 256, 0, stream>>>(Dv, dvv);
        k_scan<<<1, 1024, 0, stream>>>(Dv, offs, cur);
        k_fill<<<NN * KTOT / 256, 256, 0, stream>>>(idx, cur, adj);
        // conv1: t1 = dv * (X @ W1) ; m = De^-1 H^T t1 ; u1 = dv * H m
        k_gemm<false, true><<<dim3(HIDN / 64, NN / 64), 256, 0, stream>>>(X, W1, dvv, t1, NN, CC, HIDN);
        k_edge2<HIDN,  5,  0, 0     ><<<NN * (HIDN/4) / 256, 256, 0, stream>>>(idx, t1, m);
        k_edge2<HIDN, 10,  0, NN    ><<<NN * (HIDN/4) / 256, 256, 0, stream>>>(idx, t1, m);
        k_edge2<HIDN, 15,  0, 2*NN  ><<<NN * (HIDN/4) / 256, 256, 0, stream>>>(idx, t1, m);
        k_node2<HIDN><<<NN * (HIDN/4) / 256, 256, 0, stream>>>(offs, adj, dvv, m, u1);
        // conv2: t2 = dv * (relu(u1) @ W2) ; m = De^-1 H^T t2 ; u2 = dv * H m
        k_gemm<true, true><<<dim3(FEATN / 64, NN / 64), 256, 0, stream>>>(u1, W2, dvv, t2, NN, HIDN, FEATN);
        k_edge2<FEATN,  5, 0, 0     ><<<NN * (FEATN/4) / 256, 256, 0, stream>>>(idx, t2, m);
        k_edge2<FEATN, 10, 0, NN    ><<<NN * (FEATN/4) / 256, 256, 0, stream>>>(idx, t2, m);
        k_edge2<FEATN, 15, 0, 2*NN  ><<<NN * (FEATN/4) / 256, 256, 0, stream>>>(idx, t2, m);
        k_node2<FEATN><<<NN * (FEATN/4) / 256, 256, 0, stream>>>(offs, adj, dvv, m, u2);
        // y_s = mean over nodes, summed over features
        k_rpart<<<256, 256, 0, stream>>>(u2, part);
        k_rfinal<<<1, 256, 0, stream>>>(part, ys, s);
    }
    k_fin<<<1, 1, 0, stream>>>(ys, out);
}

// Round 3
// 1395.084 us; speedup vs baseline: 2.7558x; 1.4323x over previous
//
#include <hip/hip_runtime.h>
#include <math.h>

// DiffRankNet: HGNN forward on MI355X.
// R2: bf16 hi/lo split MFMA for Gram (XX^T) and GEMM1 (X@W1) — 3-term split
//     keeps f32-level accuracy (err ~2e-4 per dot) at MFMA rates.
//     T2 XOR-swizzled LDS (pre-swizzled global src, linear gload_lds dest,
//     swizzled ds_read_b128) -> conflict-free. Register-resident u64 top-k.
// out = [sigmoid(y0-y1), y0, y1]

#define NN   4096
#define CC   1024
#define HIDN 512
#define FEATN 128
#define NE   12288
#define KTOT 30
#define KMAX 15

typedef __attribute__((ext_vector_type(8))) short bf16x8;
typedef __attribute__((ext_vector_type(4))) float f32x4;

__device__ __forceinline__ unsigned short bf16_rne(float x) {
    unsigned u = __float_as_uint(x);
    unsigned r = (u + 0x7FFFu + ((u >> 16) & 1u)) >> 16;
    return (unsigned short)r;
}

__device__ __forceinline__ void async16(void* lds, const void* g) {
    __builtin_amdgcn_global_load_lds((const __attribute__((address_space(1))) unsigned int*)g,
                                     (__attribute__((address_space(3))) unsigned int*)lds, 16, 0, 0);
}

// ---------------- row squared norms (f32, exact as before) ----------------
__global__ __launch_bounds__(256) void k_rownorm(const float* __restrict__ X,
                                                 float* __restrict__ nrm) {
    __shared__ float s[256];
    int i = blockIdx.x, t = threadIdx.x;
    const float* row = X + (size_t)i * CC;
    float acc = 0.f;
#pragma unroll
    for (int j = 0; j < CC / 256; ++j) { float v = row[t + 256 * j]; acc += v * v; }
    s[t] = acc; __syncthreads();
    for (int d = 128; d > 0; d >>= 1) { if (t < d) s[t] += s[t + d]; __syncthreads(); }
    if (t == 0) nrm[i] = s[0];
}

// ---------------- split X -> bf16 hi/lo ----------------
__global__ __launch_bounds__(256) void k_split(const float* __restrict__ X,
                                               unsigned short* __restrict__ Xh,
                                               unsigned short* __restrict__ Xl) {
    int p = blockIdx.x * 256 + threadIdx.x;   // < NN*CC/4
    float4 v = *reinterpret_cast<const float4*>(&X[(size_t)p * 4]);
    float f[4] = { v.x, v.y, v.z, v.w };
    ushort4 H, L;
    unsigned short hh[4], ll[4];
#pragma unroll
    for (int i = 0; i < 4; ++i) {
        unsigned short hb = bf16_rne(f[i]);
        float hf = __uint_as_float((unsigned)hb << 16);
        hh[i] = hb;
        ll[i] = bf16_rne(f[i] - hf);
    }
    H.x = hh[0]; H.y = hh[1]; H.z = hh[2]; H.w = hh[3];
    L.x = ll[0]; L.y = ll[1]; L.z = ll[2]; L.w = ll[3];
    *reinterpret_cast<ushort4*>(&Xh[(size_t)p * 4]) = H;
    *reinterpret_cast<ushort4*>(&Xl[(size_t)p * 4]) = L;
}

// ---------------- transpose+split W1 [CC][HIDN] -> W1T hi/lo [HIDN][CC] ----------------
__global__ __launch_bounds__(256) void k_wt(const float* __restrict__ W,
                                            unsigned short* __restrict__ Th,
                                            unsigned short* __restrict__ Tl) {
    int p = blockIdx.x * 256 + threadIdx.x;   // < HIDN*CC
    int n = p >> 10, k = p & 1023;
    float x = W[(size_t)k * HIDN + n];
    unsigned short hb = bf16_rne(x);
    Th[p] = hb;
    Tl[p] = bf16_rne(x - __uint_as_float((unsigned)hb << 16));
}

// ---------------- bf16-split MFMA GEMM: C = [rowscale*] (A @ Bt^T) ----------------
// A rows: Ah/Al [M][1024] bf16; Bt rows: Bh/Bl [N][1024] bf16 (B^T layout).
// C[i][j] = sum_k A[i][k]*Bt[j][k] via 3-term split. BM=BN=128, BK=64, 4 waves.
// LDS: 4 panels [128][64] bf16, XOR-swizzled in 16B slots: phys_slot = log_slot ^ (row&7).
template <bool SYM, bool SCALE>
__global__ __launch_bounds__(256) void k_mm(const unsigned short* __restrict__ Ah,
                                            const unsigned short* __restrict__ Al,
                                            const unsigned short* __restrict__ Bth,
                                            const unsigned short* __restrict__ Btl,
                                            const float* __restrict__ rowscale,
                                            float* __restrict__ C, int ldc) {
    int bi = blockIdx.y, bj = blockIdx.x;
    if (SYM && bj < bi) return;
    __shared__ unsigned short lds[4][128][64];   // 64 KB
    int t = threadIdx.x;
    int w = t >> 6, l = t & 63;
    int wr = (w >> 1) * 64, wc = (w & 1) * 64;

    f32x4 acc[4][4];
#pragma unroll
    for (int i = 0; i < 4; ++i)
#pragma unroll
        for (int j = 0; j < 4; ++j) acc[i][j] = (f32x4){0.f, 0.f, 0.f, 0.f};

    const unsigned short* src[4] = {
        Ah  + (size_t)bi * 128 * 1024,
        Al  + (size_t)bi * 128 * 1024,
        Bth + (size_t)bj * 128 * 1024,
        Btl + (size_t)bj * 128 * 1024
    };
    int rloc8 = l >> 3;           // row within an 8-row issue
    int sp = l & 7;               // physical 16B slot this lane fills
    int sl = sp ^ rloc8;          // logical slot fetched (inverse-swizzled source)

    for (int kt = 0; kt < 16; ++kt) {
        int k0 = kt * 64;
        // stage: 4 panels x 4 issues/wave; linear LDS dest, pre-swizzled global src
#pragma unroll
        for (int q = 0; q < 4; ++q) {
#pragma unroll
            for (int s = 0; s < 4; ++s) {
                int rbase = (w * 4 + s) * 8;
                const unsigned short* g = src[q] + (size_t)(rbase + rloc8) * 1024 + k0 + sl * 8;
                async16(&lds[q][rbase][0], g);
            }
        }
        __syncthreads();
#pragma unroll
        for (int ks = 0; ks < 2; ++ks) {
            bf16x8 ah[4], al[4], bh[4], bl[4];
            int kg = ks * 4 + (l >> 4);   // logical 16B slot of this lane's fragment
#pragma unroll
            for (int mi = 0; mi < 4; ++mi) {
                int row = wr + mi * 16 + (l & 15);
                int ph = kg ^ (row & 7);
                ah[mi] = *reinterpret_cast<const bf16x8*>(&lds[0][row][ph * 8]);
                al[mi] = *reinterpret_cast<const bf16x8*>(&lds[1][row][ph * 8]);
            }
#pragma unroll
            for (int nj = 0; nj < 4; ++nj) {
                int row = wc + nj * 16 + (l & 15);
                int ph = kg ^ (row & 7);
                bh[nj] = *reinterpret_cast<const bf16x8*>(&lds[2][row][ph * 8]);
                bl[nj] = *reinterpret_cast<const bf16x8*>(&lds[3][row][ph * 8]);
            }
#pragma unroll
            for (int mi = 0; mi < 4; ++mi)
#pragma unroll
                for (int nj = 0; nj < 4; ++nj) {
                    acc[mi][nj] = __builtin_amdgcn_mfma_f32_16x16x32_bf16(ah[mi], bh[nj], acc[mi][nj], 0, 0, 0);
                    acc[mi][nj] = __builtin_amdgcn_mfma_f32_16x16x32_bf16(ah[mi], bl[nj], acc[mi][nj], 0, 0, 0);
                    acc[mi][nj] = __builtin_amdgcn_mfma_f32_16x16x32_bf16(al[mi], bh[nj], acc[mi][nj], 0, 0, 0);
                }
        }
        __syncthreads();
    }
    // epilogue: C/D frag mapping col=lane&15, row=(lane>>4)*4+reg
#pragma unroll
    for (int mi = 0; mi < 4; ++mi) {
#pragma unroll
        for (int r = 0; r < 4; ++r) {
            int rg = bi * 128 + wr + mi * 16 + (l >> 4) * 4 + r;
            float sc = SCALE ? rowscale[rg] : 1.0f;
#pragma unroll
            for (int nj = 0; nj < 4; ++nj) {
                int cg = bj * 128 + wc + nj * 16 + (l & 15);
                float v = acc[mi][nj][r] * sc;
                C[(size_t)rg * ldc + cg] = v;
                if (SYM && bi != bj) C[(size_t)cg * ldc + rg] = v;
            }
        }
    }
}

// ---------------- top-15: register keys, u64 (dist,idx) shfl-min ----------------
__global__ __launch_bounds__(256) void k_topk(const float* __restrict__ G,
                                              const float* __restrict__ nrm,
                                              int* __restrict__ idx_out) {
    __shared__ unsigned long long wsm[4];
    int e = blockIdx.x, t = threadIdx.x;
    float ne = nrm[e];
    const float* Grow = G + (size_t)e * NN;
    unsigned long long key[16];
    unsigned long long my = ~0ull;
#pragma unroll
    for (int j = 0; j < 16; ++j) {
        int i = t + 256 * j;
        float v = fmaxf(ne + nrm[i] - 2.0f * Grow[i], 0.0f);
        unsigned long long k = ((unsigned long long)__float_as_uint(v) << 32) | (unsigned)i;
        key[j] = k;
        my = k < my ? k : my;
    }
    for (int r = 0; r < KMAX; ++r) {
        unsigned long long m = my;
#pragma unroll
        for (int d = 1; d < 64; d <<= 1) {
            unsigned long long o = __shfl_xor(m, d);
            m = o < m ? o : m;
        }
        if ((t & 63) == 0) wsm[t >> 6] = m;
        __syncthreads();
        unsigned long long b0 = wsm[0] < wsm[1] ? wsm[0] : wsm[1];
        unsigned long long b1 = wsm[2] < wsm[3] ? wsm[2] : wsm[3];
        unsigned long long bk = b0 < b1 ? b0 : b1;
        int win = (int)(unsigned)bk;
        if (t == 0) idx_out[e * 16 + r] = win;
        if (t == (win & 255)) {
            int jw = win >> 8;
#pragma unroll
            for (int jj = 0; jj < 16; ++jj) if (jj == jw) key[jj] = ~0ull;
            my = ~0ull;
#pragma unroll
            for (int jj = 0; jj < 16; ++jj) my = key[jj] < my ? key[jj] : my;
        }
        __syncthreads();
    }
}

// ---------------- degrees / CSR ----------------
__device__ __forceinline__ void decode_pair(int p, int& e, int& b, int& j) {
    e = p / KTOT;
    int q = p - e * KTOT;
    if (q < 5)       { b = 0; j = q; }
    else if (q < 15) { b = 1; j = q - 5; }
    else             { b = 2; j = q - 15; }
}

__global__ __launch_bounds__(256) void k_count(const int* __restrict__ idx, int* __restrict__ Dv) {
    int p = blockIdx.x * 256 + threadIdx.x;
    int e, b, j; decode_pair(p, e, b, j);
    (void)b;
    atomicAdd(&Dv[idx[e * 16 + j]], 1);
}

__global__ __launch_bounds__(256) void k_dv(const int* __restrict__ Dv, float* __restrict__ dvv) {
    int i = blockIdx.x * 256 + threadIdx.x;
    int d = Dv[i];
    dvv[i] = d > 0 ? 1.0f / sqrtf((float)d) : 0.0f;
}

__global__ __launch_bounds__(1024) void k_scan(const int* __restrict__ Dv,
                                               int* __restrict__ offs,
                                               int* __restrict__ cur) {
    __shared__ int s[1024];
    int t = threadIdx.x;
    int v[4]; int sum = 0;
#pragma unroll
    for (int j = 0; j < 4; ++j) { v[j] = Dv[t * 4 + j]; sum += v[j]; }
    s[t] = sum; __syncthreads();
    for (int d = 1; d < 1024; d <<= 1) {
        int add = (t >= d) ? s[t - d] : 0;
        __syncthreads();
        s[t] += add;
        __syncthreads();
    }
    int run = s[t] - sum;
#pragma unroll
    for (int j = 0; j < 4; ++j) { offs[t * 4 + j] = run; cur[t * 4 + j] = run; run += v[j]; }
    if (t == 1023) offs[NN] = run;
}

__global__ __launch_bounds__(256) void k_fill(const int* __restrict__ idx,
                                              int* __restrict__ cur,
                                              int* __restrict__ adj) {
    int p = blockIdx.x * 256 + threadIdx.x;
    int e, b, j; decode_pair(p, e, b, j);
    int i = idx[e * 16 + j];
    int eg = b * NN + e;
    int pos = atomicAdd(&cur[i], 1);
    adj[pos] = eg;
}

// ---------------- f32 tiled GEMM (GEMM2 only): C = rowscale*(relu(A) @ B) ----------------
template <bool RELU, bool SCALE>
__global__ __launch_bounds__(256) void k_gemm(const float* __restrict__ A,
                                              const float* __restrict__ B,
                                              const float* __restrict__ rowscale,
                                              float* __restrict__ Cm,
                                              int M, int K, int Nc) {
    __shared__ float As[16][68];
    __shared__ float Bs[16][68];
    int bi = blockIdx.y, bj = blockIdx.x, t = threadIdx.x;
    int g = t >> 4, h = t & 15;
    int r0 = g * 4, c0 = h * 4;
    float acc[4][4] = {};
    for (int k0 = 0; k0 < K; k0 += 16) {
        {
            int r = t >> 2;
            int kc = (t & 3) * 4;
            float4 a = *reinterpret_cast<const float4*>(&A[(size_t)(bi * 64 + r) * K + k0 + kc]);
            if (RELU) { a.x = fmaxf(a.x, 0.f); a.y = fmaxf(a.y, 0.f); a.z = fmaxf(a.z, 0.f); a.w = fmaxf(a.w, 0.f); }
            As[kc + 0][r] = a.x; As[kc + 1][r] = a.y; As[kc + 2][r] = a.z; As[kc + 3][r] = a.w;
        }
        {
            int kr = t >> 4;
            int c = (t & 15) * 4;
            float4 b = *reinterpret_cast<const float4*>(&B[(size_t)(k0 + kr) * Nc + bj * 64 + c]);
            *reinterpret_cast<float4*>(&Bs[kr][c]) = b;
        }
        __syncthreads();
#pragma unroll
        for (int kk = 0; kk < 16; ++kk) {
            float a[4], b[4];
#pragma unroll
            for (int u = 0; u < 4; ++u) a[u] = As[kk][r0 + u];
#pragma unroll
            for (int v = 0; v < 4; ++v) b[v] = Bs[kk][c0 + v];
#pragma unroll
            for (int u = 0; u < 4; ++u)
#pragma unroll
                for (int v = 0; v < 4; ++v)
                    acc[u][v] += a[u] * b[v];
        }
        __syncthreads();
    }
#pragma unroll
    for (int u = 0; u < 4; ++u) {
        int r = bi * 64 + r0 + u;
        float sc = SCALE ? rowscale[r] : 1.0f;
        float4* p4 = reinterpret_cast<float4*>(&Cm[(size_t)r * Nc + bj * 64 + c0]);
        *p4 = make_float4(acc[u][0] * sc, acc[u][1] * sc, acc[u][2] * sc, acc[u][3] * sc);
    }
}

// ---------------- hyperedge gather ----------------
template <int F, int KB, int EB>
__global__ __launch_bounds__(256) void k_edge2(const int* __restrict__ idx,
                                               const float* __restrict__ ts,
                                               float* __restrict__ m) {
    constexpr int CPE = F / 4;
    constexpr int LG = (F == 512) ? 7 : 5;
    int p = blockIdx.x * 256 + threadIdx.x;
    int e = p >> LG;
    int c4 = (p & (CPE - 1)) * 4;
    const int* row = idx + e * 16;
    float4 acc = make_float4(0.f, 0.f, 0.f, 0.f);
#pragma unroll
    for (int j = 0; j < KB; ++j) {
        int i = row[j];
        float4 v = *reinterpret_cast<const float4*>(&ts[(size_t)i * F + c4]);
        acc.x += v.x; acc.y += v.y; acc.z += v.z; acc.w += v.w;
    }
    constexpr float de = 1.0f / (float)KB;
    float4* o = reinterpret_cast<float4*>(&m[(size_t)(EB + e) * F + c4]);
    *o = make_float4(acc.x * de, acc.y * de, acc.z * de, acc.w * de);
}

// ---------------- node gather ----------------
template <int F>
__global__ __launch_bounds__(256) void k_node2(const int* __restrict__ offs,
                                               const int* __restrict__ adj,
                                               const float* __restrict__ dvv,
                                               const float* __restrict__ m,
                                               float* __restrict__ u) {
    constexpr int CPN = F / 4;
    constexpr int LG = (F == 512) ? 7 : 5;
    int p = blockIdx.x * 256 + threadIdx.x;
    int i = p >> LG;
    int c4 = (p & (CPN - 1)) * 4;
    int q0 = offs[i], q1 = offs[i + 1];
    float4 acc = make_float4(0.f, 0.f, 0.f, 0.f);
    int q = q0;
    for (; q + 4 <= q1; q += 4) {
        int e0 = adj[q], e1 = adj[q + 1], e2 = adj[q + 2], e3 = adj[q + 3];
        float4 v0 = *reinterpret_cast<const float4*>(&m[(size_t)e0 * F + c4]);
        float4 v1 = *reinterpret_cast<const float4*>(&m[(size_t)e1 * F + c4]);
        float4 v2 = *reinterpret_cast<const float4*>(&m[(size_t)e2 * F + c4]);
        float4 v3 = *reinterpret_cast<const float4*>(&m[(size_t)e3 * F + c4]);
        acc.x += v0.x + v1.x + v2.x + v3.x;
        acc.y += v0.y + v1.y + v2.y + v3.y;
        acc.z += v0.z + v1.z + v2.z + v3.z;
        acc.w += v0.w + v1.w + v2.w + v3.w;
    }
    for (; q < q1; ++q) {
        float4 v = *reinterpret_cast<const float4*>(&m[(size_t)adj[q] * F + c4]);
        acc.x += v.x; acc.y += v.y; acc.z += v.z; acc.w += v.w;
    }
    float dv = dvv[i];
    float4* o = reinterpret_cast<float4*>(&u[(size_t)i * F + c4]);
    *o = make_float4(acc.x * dv, acc.y * dv, acc.z * dv, acc.w * dv);
}

// ---------------- reductions ----------------
__global__ __launch_bounds__(256) void k_rpart(const float* __restrict__ u2, float* __restrict__ part) {
    __shared__ float s[256];
    float acc = 0.f;
    for (int i = blockIdx.x * 256 + threadIdx.x; i < NN * FEATN; i += 256 * 256) acc += u2[i];
    s[threadIdx.x] = acc; __syncthreads();
    for (int d = 128; d > 0; d >>= 1) { if (threadIdx.x < d) s[threadIdx.x] += s[threadIdx.x + d]; __syncthreads(); }
    if (threadIdx.x == 0) part[blockIdx.x] = s[0];
}

__global__ __launch_bounds__(256) void k_rfinal(const float* __restrict__ part, float* __restrict__ ys, int slot) {
    __shared__ float s[256];
    s[threadIdx.x] = part[threadIdx.x]; __syncthreads();
    for (int d = 128; d > 0; d >>= 1) { if (threadIdx.x < d) s[threadIdx.x] += s[threadIdx.x + d]; __syncthreads(); }
    if (threadIdx.x == 0) ys[slot] = s[0] / (float)NN;
}

__global__ void k_fin(const float* __restrict__ ys, float* __restrict__ out) {
    float y0 = ys[0], y1 = ys[1];
    out[0] = 1.0f / (1.0f + expf(-(y0 - y1)));
    out[1] = y0;
    out[2] = y1;
}

// ---------------- launch ----------------
extern "C" void kernel_launch(void* const* d_in, const int* in_sizes, int n_in,
                              void* d_out, int out_size, void* d_ws, size_t ws_size,
                              hipStream_t stream) {
    const float* fts[2] = { (const float*)d_in[0], (const float*)d_in[1] };
    const float* W1 = (const float*)d_in[2];
    const float* W2 = (const float*)d_in[3];
    float* out = (float*)d_out;

    char* p = (char*)d_ws;
    auto alloc = [&](size_t b) { char* r = p; p += (b + 255) & ~(size_t)255; return r; };
    float* G    = (float*)alloc((size_t)NN * NN * 4);        // 64 MB
    float* nrm  = (float*)alloc((size_t)NN * 4);
    int*   idx  = (int*)  alloc((size_t)NN * 16 * 4);
    int*   Dv   = (int*)  alloc((size_t)NN * 4);
    float* dvv  = (float*)alloc((size_t)NN * 4);
    int*   offs = (int*)  alloc((size_t)(NN + 1) * 4);
    int*   cur  = (int*)  alloc((size_t)NN * 4);
    int*   adj  = (int*)  alloc((size_t)NN * KTOT * 4);
    float* t1   = (float*)alloc((size_t)NN * HIDN * 4);
    float* u1   = (float*)alloc((size_t)NN * HIDN * 4);
    float* t2   = (float*)alloc((size_t)NN * FEATN * 4);
    float* u2   = (float*)alloc((size_t)NN * FEATN * 4);
    float* m    = (float*)alloc((size_t)NE * HIDN * 4);      // 25 MB; Xh/Xl alias this (16.8MB),
                                                             // consumed before k_edge2 writes m
    unsigned short* W1Th = (unsigned short*)alloc((size_t)HIDN * CC * 2);
    unsigned short* W1Tl = (unsigned short*)alloc((size_t)HIDN * CC * 2);
    float* part = (float*)alloc(256 * 4);
    float* ys   = (float*)alloc(2 * 4);

    unsigned short* Xh = (unsigned short*)m;                 // [NN][CC] bf16 hi
    unsigned short* Xl = Xh + (size_t)NN * CC;               // [NN][CC] bf16 lo

    k_wt<<<HIDN * CC / 256, 256, 0, stream>>>(W1, W1Th, W1Tl);

    for (int s = 0; s < 2; ++s) {
        const float* X = fts[s];
        k_rownorm<<<NN, 256, 0, stream>>>(X, nrm);
        k_split<<<NN * CC / 4 / 256, 256, 0, stream>>>(X, Xh, Xl);
        // Gram: G = X X^T via 3-term bf16 split, symmetric blocks
        k_mm<true, false><<<dim3(NN / 128, NN / 128), 256, 0, stream>>>(Xh, Xl, Xh, Xl, nullptr, G, NN);
        k_topk<<<NN, 256, 0, stream>>>(G, nrm, idx);
        hipMemsetAsync(Dv, 0, NN * 4, stream);
        k_count<<<NN * KTOT / 256, 256, 0, stream>>>(idx, Dv);
        k_dv<<<NN / 256, 256, 0, stream>>>(Dv, dvv);
        k_scan<<<1, 1024, 0, stream>>>(Dv, offs, cur);
        k_fill<<<NN * KTOT / 256, 256, 0, stream>>>(idx, cur, adj);
        // conv1: t1 = dv * (X @ W1) via split MFMA; then sparse A-apply
        k_mm<false, true><<<dim3(HIDN / 128, NN / 128), 256, 0, stream>>>(Xh, Xl, W1Th, W1Tl, dvv, t1, HIDN);
        k_edge2<HIDN,  5, 0     ><<<NN * (HIDN / 4) / 256, 256, 0, stream>>>(idx, t1, m);
        k_edge2<HIDN, 10, NN    ><<<NN * (HIDN / 4) / 256, 256, 0, stream>>>(idx, t1, m);
        k_edge2<HIDN, 15, 2 * NN><<<NN * (HIDN / 4) / 256, 256, 0, stream>>>(idx, t1, m);
        k_node2<HIDN><<<NN * (HIDN / 4) / 256, 256, 0, stream>>>(offs, adj, dvv, m, u1);
        // conv2: t2 = dv * (relu(u1) @ W2) f32; then sparse A-apply
        k_gemm<true, true><<<dim3(FEATN / 64, NN / 64), 256, 0, stream>>>(u1, W2, dvv, t2, NN, HIDN, FEATN);
        k_edge2<FEATN,  5, 0     ><<<NN * (FEATN / 4) / 256, 256, 0, stream>>>(idx, t2, m);
        k_edge2<FEATN, 10, NN    ><<<NN * (FEATN / 4) / 256, 256, 0, stream>>>(idx, t2, m);
        k_edge2<FEATN, 15, 2 * NN><<<NN * (FEATN / 4) / 256, 256, 0, stream>>>(idx, t2, m);
        k_node2<FEATN><<<NN * (FEATN / 4) / 256, 256, 0, stream>>>(offs, adj, dvv, m, u2);
        k_rpart<<<256, 256, 0, stream>>>(u2, part);
        k_rfinal<<<1, 256, 0, stream>>>(part, ys, s);
    }
    k_fin<<<1, 1, 0, stream>>>(ys, out);
}

// Round 4
// 857.743 us; speedup vs baseline: 4.4822x; 1.6265x over previous
//
#include <hip/hip_runtime.h>
#include <math.h>

// DiffRankNet: HGNN forward on MI355X.
// R3: load-balanced node gather — degree-chunked (16 adj entries/task) partial
//     sums + combine pass. Fixes the hub-node straggler tail that made
//     k_node2 run at 4.7% occupancy / 1.3% VALUBusy.
// out = [sigmoid(y0-y1), y0, y1]

#define NN   4096
#define CC   1024
#define HIDN 512
#define FEATN 128
#define NE   12288
#define KTOT 30
#define KMAX 15
#define CH   16                      // adj entries per chunk task
#define MAXCH (NN + NN * KTOT / CH)  // 11776 upper bound on total chunks

typedef __attribute__((ext_vector_type(8))) short bf16x8;
typedef __attribute__((ext_vector_type(4))) float f32x4;

__device__ __forceinline__ unsigned short bf16_rne(float x) {
    unsigned u = __float_as_uint(x);
    unsigned r = (u + 0x7FFFu + ((u >> 16) & 1u)) >> 16;
    return (unsigned short)r;
}

__device__ __forceinline__ void async16(void* lds, const void* g) {
    __builtin_amdgcn_global_load_lds((const __attribute__((address_space(1))) unsigned int*)g,
                                     (__attribute__((address_space(3))) unsigned int*)lds, 16, 0, 0);
}

// ---------------- row squared norms ----------------
__global__ __launch_bounds__(256) void k_rownorm(const float* __restrict__ X,
                                                 float* __restrict__ nrm) {
    __shared__ float s[256];
    int i = blockIdx.x, t = threadIdx.x;
    const float* row = X + (size_t)i * CC;
    float acc = 0.f;
#pragma unroll
    for (int j = 0; j < CC / 256; ++j) { float v = row[t + 256 * j]; acc += v * v; }
    s[t] = acc; __syncthreads();
    for (int d = 128; d > 0; d >>= 1) { if (t < d) s[t] += s[t + d]; __syncthreads(); }
    if (t == 0) nrm[i] = s[0];
}

// ---------------- split X -> bf16 hi/lo ----------------
__global__ __launch_bounds__(256) void k_split(const float* __restrict__ X,
                                               unsigned short* __restrict__ Xh,
                                               unsigned short* __restrict__ Xl) {
    int p = blockIdx.x * 256 + threadIdx.x;
    float4 v = *reinterpret_cast<const float4*>(&X[(size_t)p * 4]);
    float f[4] = { v.x, v.y, v.z, v.w };
    ushort4 H, L;
    unsigned short hh[4], ll[4];
#pragma unroll
    for (int i = 0; i < 4; ++i) {
        unsigned short hb = bf16_rne(f[i]);
        float hf = __uint_as_float((unsigned)hb << 16);
        hh[i] = hb;
        ll[i] = bf16_rne(f[i] - hf);
    }
    H.x = hh[0]; H.y = hh[1]; H.z = hh[2]; H.w = hh[3];
    L.x = ll[0]; L.y = ll[1]; L.z = ll[2]; L.w = ll[3];
    *reinterpret_cast<ushort4*>(&Xh[(size_t)p * 4]) = H;
    *reinterpret_cast<ushort4*>(&Xl[(size_t)p * 4]) = L;
}

// ---------------- transpose+split W1 ----------------
__global__ __launch_bounds__(256) void k_wt(const float* __restrict__ W,
                                            unsigned short* __restrict__ Th,
                                            unsigned short* __restrict__ Tl) {
    int p = blockIdx.x * 256 + threadIdx.x;
    int n = p >> 10, k = p & 1023;
    float x = W[(size_t)k * HIDN + n];
    unsigned short hb = bf16_rne(x);
    Th[p] = hb;
    Tl[p] = bf16_rne(x - __uint_as_float((unsigned)hb << 16));
}

// ---------------- bf16-split MFMA GEMM ----------------
template <bool SYM, bool SCALE>
__global__ __launch_bounds__(256) void k_mm(const unsigned short* __restrict__ Ah,
                                            const unsigned short* __restrict__ Al,
                                            const unsigned short* __restrict__ Bth,
                                            const unsigned short* __restrict__ Btl,
                                            const float* __restrict__ rowscale,
                                            float* __restrict__ C, int ldc) {
    int bi = blockIdx.y, bj = blockIdx.x;
    if (SYM && bj < bi) return;
    __shared__ unsigned short lds[4][128][64];
    int t = threadIdx.x;
    int w = t >> 6, l = t & 63;
    int wr = (w >> 1) * 64, wc = (w & 1) * 64;

    f32x4 acc[4][4];
#pragma unroll
    for (int i = 0; i < 4; ++i)
#pragma unroll
        for (int j = 0; j < 4; ++j) acc[i][j] = (f32x4){0.f, 0.f, 0.f, 0.f};

    const unsigned short* src[4] = {
        Ah  + (size_t)bi * 128 * 1024,
        Al  + (size_t)bi * 128 * 1024,
        Bth + (size_t)bj * 128 * 1024,
        Btl + (size_t)bj * 128 * 1024
    };
    int rloc8 = l >> 3;
    int sp = l & 7;
    int sl = sp ^ rloc8;

    for (int kt = 0; kt < 16; ++kt) {
        int k0 = kt * 64;
#pragma unroll
        for (int q = 0; q < 4; ++q) {
#pragma unroll
            for (int s = 0; s < 4; ++s) {
                int rbase = (w * 4 + s) * 8;
                const unsigned short* g = src[q] + (size_t)(rbase + rloc8) * 1024 + k0 + sl * 8;
                async16(&lds[q][rbase][0], g);
            }
        }
        __syncthreads();
#pragma unroll
        for (int ks = 0; ks < 2; ++ks) {
            bf16x8 ah[4], al[4], bh[4], bl[4];
            int kg = ks * 4 + (l >> 4);
#pragma unroll
            for (int mi = 0; mi < 4; ++mi) {
                int row = wr + mi * 16 + (l & 15);
                int ph = kg ^ (row & 7);
                ah[mi] = *reinterpret_cast<const bf16x8*>(&lds[0][row][ph * 8]);
                al[mi] = *reinterpret_cast<const bf16x8*>(&lds[1][row][ph * 8]);
            }
#pragma unroll
            for (int nj = 0; nj < 4; ++nj) {
                int row = wc + nj * 16 + (l & 15);
                int ph = kg ^ (row & 7);
                bh[nj] = *reinterpret_cast<const bf16x8*>(&lds[2][row][ph * 8]);
                bl[nj] = *reinterpret_cast<const bf16x8*>(&lds[3][row][ph * 8]);
            }
#pragma unroll
            for (int mi = 0; mi < 4; ++mi)
#pragma unroll
                for (int nj = 0; nj < 4; ++nj) {
                    acc[mi][nj] = __builtin_amdgcn_mfma_f32_16x16x32_bf16(ah[mi], bh[nj], acc[mi][nj], 0, 0, 0);
                    acc[mi][nj] = __builtin_amdgcn_mfma_f32_16x16x32_bf16(ah[mi], bl[nj], acc[mi][nj], 0, 0, 0);
                    acc[mi][nj] = __builtin_amdgcn_mfma_f32_16x16x32_bf16(al[mi], bh[nj], acc[mi][nj], 0, 0, 0);
                }
        }
        __syncthreads();
    }
#pragma unroll
    for (int mi = 0; mi < 4; ++mi) {
#pragma unroll
        for (int r = 0; r < 4; ++r) {
            int rg = bi * 128 + wr + mi * 16 + (l >> 4) * 4 + r;
            float sc = SCALE ? rowscale[rg] : 1.0f;
#pragma unroll
            for (int nj = 0; nj < 4; ++nj) {
                int cg = bj * 128 + wc + nj * 16 + (l & 15);
                float v = acc[mi][nj][r] * sc;
                C[(size_t)rg * ldc + cg] = v;
                if (SYM && bi != bj) C[(size_t)cg * ldc + rg] = v;
            }
        }
    }
}

// ---------------- top-15: register keys, u64 shfl-min ----------------
__global__ __launch_bounds__(256) void k_topk(const float* __restrict__ G,
                                              const float* __restrict__ nrm,
                                              int* __restrict__ idx_out) {
    __shared__ unsigned long long wsm[4];
    int e = blockIdx.x, t = threadIdx.x;
    float ne = nrm[e];
    const float* Grow = G + (size_t)e * NN;
    unsigned long long key[16];
    unsigned long long my = ~0ull;
#pragma unroll
    for (int j = 0; j < 16; ++j) {
        int i = t + 256 * j;
        float v = fmaxf(ne + nrm[i] - 2.0f * Grow[i], 0.0f);
        unsigned long long k = ((unsigned long long)__float_as_uint(v) << 32) | (unsigned)i;
        key[j] = k;
        my = k < my ? k : my;
    }
    for (int r = 0; r < KMAX; ++r) {
        unsigned long long m = my;
#pragma unroll
        for (int d = 1; d < 64; d <<= 1) {
            unsigned long long o = __shfl_xor(m, d);
            m = o < m ? o : m;
        }
        if ((t & 63) == 0) wsm[t >> 6] = m;
        __syncthreads();
        unsigned long long b0 = wsm[0] < wsm[1] ? wsm[0] : wsm[1];
        unsigned long long b1 = wsm[2] < wsm[3] ? wsm[2] : wsm[3];
        unsigned long long bk = b0 < b1 ? b0 : b1;
        int win = (int)(unsigned)bk;
        if (t == 0) idx_out[e * 16 + r] = win;
        if (t == (win & 255)) {
            int jw = win >> 8;
#pragma unroll
            for (int jj = 0; jj < 16; ++jj) if (jj == jw) key[jj] = ~0ull;
            my = ~0ull;
#pragma unroll
            for (int jj = 0; jj < 16; ++jj) my = key[jj] < my ? key[jj] : my;
        }
        __syncthreads();
    }
}

// ---------------- degrees / CSR ----------------
__device__ __forceinline__ void decode_pair(int p, int& e, int& b, int& j) {
    e = p / KTOT;
    int q = p - e * KTOT;
    if (q < 5)       { b = 0; j = q; }
    else if (q < 15) { b = 1; j = q - 5; }
    else             { b = 2; j = q - 15; }
}

__global__ __launch_bounds__(256) void k_count(const int* __restrict__ idx, int* __restrict__ Dv) {
    int p = blockIdx.x * 256 + threadIdx.x;
    int e, b, j; decode_pair(p, e, b, j);
    (void)b;
    atomicAdd(&Dv[idx[e * 16 + j]], 1);
}

__global__ __launch_bounds__(256) void k_dv(const int* __restrict__ Dv, float* __restrict__ dvv) {
    int i = blockIdx.x * 256 + threadIdx.x;
    int d = Dv[i];
    dvv[i] = d > 0 ? 1.0f / sqrtf((float)d) : 0.0f;
}

// scan of degrees (offs/cur) AND of per-node chunk counts (chunkoffs, nchunks)
__global__ __launch_bounds__(1024) void k_scan(const int* __restrict__ Dv,
                                               int* __restrict__ offs,
                                               int* __restrict__ cur,
                                               int* __restrict__ chunkoffs,
                                               int* __restrict__ nchunks) {
    __shared__ int s[1024];
    int t = threadIdx.x;
    int v[4]; int sum = 0;
#pragma unroll
    for (int j = 0; j < 4; ++j) { v[j] = Dv[t * 4 + j]; sum += v[j]; }
    s[t] = sum; __syncthreads();
    for (int d = 1; d < 1024; d <<= 1) {
        int add = (t >= d) ? s[t - d] : 0;
        __syncthreads();
        s[t] += add;
        __syncthreads();
    }
    int run = s[t] - sum;
#pragma unroll
    for (int j = 0; j < 4; ++j) { offs[t * 4 + j] = run; cur[t * 4 + j] = run; run += v[j]; }
    if (t == 1023) offs[NN] = run;
    __syncthreads();
    // chunk-count scan
    int c[4]; int csum = 0;
#pragma unroll
    for (int j = 0; j < 4; ++j) { c[j] = (v[j] + CH - 1) / CH; csum += c[j]; }
    s[t] = csum; __syncthreads();
    for (int d = 1; d < 1024; d <<= 1) {
        int add = (t >= d) ? s[t - d] : 0;
        __syncthreads();
        s[t] += add;
        __syncthreads();
    }
    int crun = s[t] - csum;
#pragma unroll
    for (int j = 0; j < 4; ++j) { chunkoffs[t * 4 + j] = crun; crun += c[j]; }
    if (t == 1023) { chunkoffs[NN] = crun; *nchunks = crun; }
}

__global__ __launch_bounds__(256) void k_fill(const int* __restrict__ idx,
                                              int* __restrict__ cur,
                                              int* __restrict__ adj) {
    int p = blockIdx.x * 256 + threadIdx.x;
    int e, b, j; decode_pair(p, e, b, j);
    int i = idx[e * 16 + j];
    int eg = b * NN + e;
    int pos = atomicAdd(&cur[i], 1);
    adj[pos] = eg;
}

__global__ __launch_bounds__(256) void k_tasks(const int* __restrict__ chunkoffs,
                                               int* __restrict__ task_node) {
    int i = blockIdx.x * 256 + threadIdx.x;   // NN
    int c0 = chunkoffs[i], c1 = chunkoffs[i + 1];
    for (int c = c0; c < c1; ++c) task_node[c] = i;
}

// ---------------- chunked node gather: partial[task] = sum of <=CH edge rows ----------------
template <int F>
__global__ __launch_bounds__(256) void k_chunk(const int* __restrict__ offs,
                                               const int* __restrict__ chunkoffs,
                                               const int* __restrict__ task_node,
                                               const int* __restrict__ nchunks,
                                               const int* __restrict__ adj,
                                               const float* __restrict__ m,
                                               float* __restrict__ partial) {
    constexpr int TPN = F / 4;          // threads per task
    constexpr int TB = 256 / TPN;       // tasks per block
    int task = blockIdx.x * TB + threadIdx.x / TPN;
    if (task >= *nchunks) return;
    int c4 = (threadIdx.x % TPN) * 4;
    int i = task_node[task];
    int ck = task - chunkoffs[i];
    int q0 = offs[i] + ck * CH;
    int n = offs[i + 1] - q0;
    n = n < CH ? n : CH;
    int e[CH];
#pragma unroll
    for (int j = 0; j < CH; ++j) e[j] = (j < n) ? adj[q0 + j] : -1;
    float4 acc = make_float4(0.f, 0.f, 0.f, 0.f);
#pragma unroll
    for (int j = 0; j < CH; ++j) {
        if (e[j] >= 0) {
            float4 v = *reinterpret_cast<const float4*>(&m[(size_t)e[j] * F + c4]);
            acc.x += v.x; acc.y += v.y; acc.z += v.z; acc.w += v.w;
        }
    }
    *reinterpret_cast<float4*>(&partial[(size_t)task * F + c4]) = acc;
}

// ---------------- combine: u[i] = dv_i * sum of node i's chunk partials ----------------
template <int F>
__global__ __launch_bounds__(256) void k_comb(const int* __restrict__ chunkoffs,
                                              const float* __restrict__ dvv,
                                              const float* __restrict__ partial,
                                              float* __restrict__ u) {
    constexpr int CPN = F / 4;
    constexpr int LG = (F == 512) ? 7 : 5;
    int p = blockIdx.x * 256 + threadIdx.x;
    int i = p >> LG;
    int c4 = (p & (CPN - 1)) * 4;
    int c0 = chunkoffs[i], c1 = chunkoffs[i + 1];
    float4 acc = make_float4(0.f, 0.f, 0.f, 0.f);
    for (int c = c0; c < c1; ++c) {
        float4 v = *reinterpret_cast<const float4*>(&partial[(size_t)c * F + c4]);
        acc.x += v.x; acc.y += v.y; acc.z += v.z; acc.w += v.w;
    }
    float dv = dvv[i];
    float4* o = reinterpret_cast<float4*>(&u[(size_t)i * F + c4]);
    *o = make_float4(acc.x * dv, acc.y * dv, acc.z * dv, acc.w * dv);
}

// ---------------- f32 tiled GEMM (GEMM2): C = rowscale*(relu(A) @ B) ----------------
template <bool RELU, bool SCALE>
__global__ __launch_bounds__(256) void k_gemm(const float* __restrict__ A,
                                              const float* __restrict__ B,
                                              const float* __restrict__ rowscale,
                                              float* __restrict__ Cm,
                                              int M, int K, int Nc) {
    __shared__ float As[16][68];
    __shared__ float Bs[16][68];
    int bi = blockIdx.y, bj = blockIdx.x, t = threadIdx.x;
    int g = t >> 4, h = t & 15;
    int r0 = g * 4, c0 = h * 4;
    float acc[4][4] = {};
    for (int k0 = 0; k0 < K; k0 += 16) {
        {
            int r = t >> 2;
            int kc = (t & 3) * 4;
            float4 a = *reinterpret_cast<const float4*>(&A[(size_t)(bi * 64 + r) * K + k0 + kc]);
            if (RELU) { a.x = fmaxf(a.x, 0.f); a.y = fmaxf(a.y, 0.f); a.z = fmaxf(a.z, 0.f); a.w = fmaxf(a.w, 0.f); }
            As[kc + 0][r] = a.x; As[kc + 1][r] = a.y; As[kc + 2][r] = a.z; As[kc + 3][r] = a.w;
        }
        {
            int kr = t >> 4;
            int c = (t & 15) * 4;
            float4 b = *reinterpret_cast<const float4*>(&B[(size_t)(k0 + kr) * Nc + bj * 64 + c]);
            *reinterpret_cast<float4*>(&Bs[kr][c]) = b;
        }
        __syncthreads();
#pragma unroll
        for (int kk = 0; kk < 16; ++kk) {
            float a[4], b[4];
#pragma unroll
            for (int u = 0; u < 4; ++u) a[u] = As[kk][r0 + u];
#pragma unroll
            for (int v = 0; v < 4; ++v) b[v] = Bs[kk][c0 + v];
#pragma unroll
            for (int u = 0; u < 4; ++u)
#pragma unroll
                for (int v = 0; v < 4; ++v)
                    acc[u][v] += a[u] * b[v];
        }
        __syncthreads();
    }
#pragma unroll
    for (int u = 0; u < 4; ++u) {
        int r = bi * 64 + r0 + u;
        float sc = SCALE ? rowscale[r] : 1.0f;
        float4* p4 = reinterpret_cast<float4*>(&Cm[(size_t)r * Nc + bj * 64 + c0]);
        *p4 = make_float4(acc[u][0] * sc, acc[u][1] * sc, acc[u][2] * sc, acc[u][3] * sc);
    }
}

// ---------------- hyperedge gather ----------------
template <int F, int KB, int EB>
__global__ __launch_bounds__(256) void k_edge2(const int* __restrict__ idx,
                                               const float* __restrict__ ts,
                                               float* __restrict__ m) {
    constexpr int CPE = F / 4;
    constexpr int LG = (F == 512) ? 7 : 5;
    int p = blockIdx.x * 256 + threadIdx.x;
    int e = p >> LG;
    int c4 = (p & (CPE - 1)) * 4;
    const int* row = idx + e * 16;
    float4 acc = make_float4(0.f, 0.f, 0.f, 0.f);
#pragma unroll
    for (int j = 0; j < KB; ++j) {
        int i = row[j];
        float4 v = *reinterpret_cast<const float4*>(&ts[(size_t)i * F + c4]);
        acc.x += v.x; acc.y += v.y; acc.z += v.z; acc.w += v.w;
    }
    constexpr float de = 1.0f / (float)KB;
    float4* o = reinterpret_cast<float4*>(&m[(size_t)(EB + e) * F + c4]);
    *o = make_float4(acc.x * de, acc.y * de, acc.z * de, acc.w * de);
}

// ---------------- reductions ----------------
__global__ __launch_bounds__(256) void k_rpart(const float* __restrict__ u2, float* __restrict__ part) {
    __shared__ float s[256];
    float acc = 0.f;
    for (int i = blockIdx.x * 256 + threadIdx.x; i < NN * FEATN; i += 256 * 256) acc += u2[i];
    s[threadIdx.x] = acc; __syncthreads();
    for (int d = 128; d > 0; d >>= 1) { if (threadIdx.x < d) s[threadIdx.x] += s[threadIdx.x + d]; __syncthreads(); }
    if (threadIdx.x == 0) part[blockIdx.x] = s[0];
}

__global__ __launch_bounds__(256) void k_rfinal(const float* __restrict__ part, float* __restrict__ ys, int slot) {
    __shared__ float s[256];
    s[threadIdx.x] = part[threadIdx.x]; __syncthreads();
    for (int d = 128; d > 0; d >>= 1) { if (threadIdx.x < d) s[threadIdx.x] += s[threadIdx.x + d]; __syncthreads(); }
    if (threadIdx.x == 0) ys[slot] = s[0] / (float)NN;
}

__global__ void k_fin(const float* __restrict__ ys, float* __restrict__ out) {
    float y0 = ys[0], y1 = ys[1];
    out[0] = 1.0f / (1.0f + expf(-(y0 - y1)));
    out[1] = y0;
    out[2] = y1;
}

// ---------------- launch ----------------
extern "C" void kernel_launch(void* const* d_in, const int* in_sizes, int n_in,
                              void* d_out, int out_size, void* d_ws, size_t ws_size,
                              hipStream_t stream) {
    const float* fts[2] = { (const float*)d_in[0], (const float*)d_in[1] };
    const float* W1 = (const float*)d_in[2];
    const float* W2 = (const float*)d_in[3];
    float* out = (float*)d_out;

    char* p = (char*)d_ws;
    auto alloc = [&](size_t b) { char* r = p; p += (b + 255) & ~(size_t)255; return r; };
    float* G    = (float*)alloc((size_t)NN * NN * 4);        // 64 MB; reused as chunk-partial buffer
    float* nrm  = (float*)alloc((size_t)NN * 4);
    int*   idx  = (int*)  alloc((size_t)NN * 16 * 4);
    int*   Dv   = (int*)  alloc((size_t)NN * 4);
    float* dvv  = (float*)alloc((size_t)NN * 4);
    int*   offs = (int*)  alloc((size_t)(NN + 1) * 4);
    int*   cur  = (int*)  alloc((size_t)NN * 4);
    int*   coffs= (int*)  alloc((size_t)(NN + 1) * 4);
    int*   nch  = (int*)  alloc(4);
    int*   tnode= (int*)  alloc((size_t)MAXCH * 4);
    int*   adj  = (int*)  alloc((size_t)NN * KTOT * 4);
    float* t1   = (float*)alloc((size_t)NN * HIDN * 4);
    float* u1   = (float*)alloc((size_t)NN * HIDN * 4);
    float* t2   = (float*)alloc((size_t)NN * FEATN * 4);
    float* u2   = (float*)alloc((size_t)NN * FEATN * 4);
    float* m    = (float*)alloc((size_t)NE * HIDN * 4);      // 25 MB; Xh/Xl alias (consumed first)
    unsigned short* W1Th = (unsigned short*)alloc((size_t)HIDN * CC * 2);
    unsigned short* W1Tl = (unsigned short*)alloc((size_t)HIDN * CC * 2);
    float* part = (float*)alloc(256 * 4);
    float* ys   = (float*)alloc(2 * 4);

    unsigned short* Xh = (unsigned short*)m;
    unsigned short* Xl = Xh + (size_t)NN * CC;
    float* partial = G;   // chunk partials alias G (free after k_topk); <=24 MB

    k_wt<<<HIDN * CC / 256, 256, 0, stream>>>(W1, W1Th, W1Tl);

    for (int s = 0; s < 2; ++s) {
        const float* X = fts[s];
        k_rownorm<<<NN, 256, 0, stream>>>(X, nrm);
        k_split<<<NN * CC / 4 / 256, 256, 0, stream>>>(X, Xh, Xl);
        k_mm<true, false><<<dim3(NN / 128, NN / 128), 256, 0, stream>>>(Xh, Xl, Xh, Xl, nullptr, G, NN);
        k_topk<<<NN, 256, 0, stream>>>(G, nrm, idx);
        hipMemsetAsync(Dv, 0, NN * 4, stream);
        k_count<<<NN * KTOT / 256, 256, 0, stream>>>(idx, Dv);
        k_dv<<<NN / 256, 256, 0, stream>>>(Dv, dvv);
        k_scan<<<1, 1024, 0, stream>>>(Dv, offs, cur, coffs, nch);
        k_fill<<<NN * KTOT / 256, 256, 0, stream>>>(idx, cur, adj);
        k_tasks<<<NN / 256, 256, 0, stream>>>(coffs, tnode);
        // conv1: t1 = dv * (X @ W1); m = De^-1 H^T t1; u1 = dv * H m (chunked)
        k_mm<false, true><<<dim3(HIDN / 128, NN / 128), 256, 0, stream>>>(Xh, Xl, W1Th, W1Tl, dvv, t1, HIDN);
        k_edge2<HIDN,  5, 0     ><<<NN * (HIDN / 4) / 256, 256, 0, stream>>>(idx, t1, m);
        k_edge2<HIDN, 10, NN    ><<<NN * (HIDN / 4) / 256, 256, 0, stream>>>(idx, t1, m);
        k_edge2<HIDN, 15, 2 * NN><<<NN * (HIDN / 4) / 256, 256, 0, stream>>>(idx, t1, m);
        k_chunk<HIDN><<<MAXCH / 2, 256, 0, stream>>>(offs, coffs, tnode, nch, adj, m, partial);
        k_comb<HIDN><<<NN * (HIDN / 4) / 256, 256, 0, stream>>>(coffs, dvv, partial, u1);
        // conv2: t2 = dv * (relu(u1) @ W2); m = De^-1 H^T t2; u2 = dv * H m (chunked)
        k_gemm<true, true><<<dim3(FEATN / 64, NN / 64), 256, 0, stream>>>(u1, W2, dvv, t2, NN, HIDN, FEATN);
        k_edge2<FEATN,  5, 0     ><<<NN * (FEATN / 4) / 256, 256, 0, stream>>>(idx, t2, m);
        k_edge2<FEATN, 10, NN    ><<<NN * (FEATN / 4) / 256, 256, 0, stream>>>(idx, t2, m);
        k_edge2<FEATN, 15, 2 * NN><<<NN * (FEATN / 4) / 256, 256, 0, stream>>>(idx, t2, m);
        k_chunk<FEATN><<<MAXCH / 8, 256, 0, stream>>>(offs, coffs, tnode, nch, adj, m, partial);
        k_comb<FEATN><<<NN * (FEATN / 4) / 256, 256, 0, stream>>>(coffs, dvv, partial, u2);
        k_rpart<<<256, 256, 0, stream>>>(u2, part);
        k_rfinal<<<1, 256, 0, stream>>>(part, ys, s);
    }
    k_fin<<<1, 1, 0, stream>>>(ys, out);
}

// Round 5
// 771.260 us; speedup vs baseline: 4.9848x; 1.1121x over previous
//
#include <hip/hip_runtime.h>
#include <math.h>

// DiffRankNet: HGNN forward on MI355X.
// R4: (1) layer-2 collapsed to y = a^T relu(u1) wbar / N  (A symmetric);
//     (2) incremental edge sums (15 reads serve k=5/10/15);
//     (3) coalesced W1 transpose; (4) Gram: triangle-linear grid + XCD-chunked
//     remap for L2 panel reuse (staging was L3-BW-bound).
// out = [sigmoid(y0-y1), y0, y1]

#define NN   4096
#define CC   1024
#define HIDN 512
#define FEATN 128
#define NE   12288
#define KTOT 30
#define KMAX 15
#define CH   16
#define MAXCH (NN + NN * KTOT / CH)

typedef __attribute__((ext_vector_type(8))) short bf16x8;
typedef __attribute__((ext_vector_type(4))) float f32x4;
typedef unsigned short ushort_t;

__device__ __forceinline__ unsigned short bf16_rne(float x) {
    unsigned u = __float_as_uint(x);
    unsigned r = (u + 0x7FFFu + ((u >> 16) & 1u)) >> 16;
    return (unsigned short)r;
}

__device__ __forceinline__ void async16(void* lds, const void* g) {
    __builtin_amdgcn_global_load_lds((const __attribute__((address_space(1))) unsigned int*)g,
                                     (__attribute__((address_space(3))) unsigned int*)lds, 16, 0, 0);
}

// ---------------- row squared norms ----------------
__global__ __launch_bounds__(256) void k_rownorm(const float* __restrict__ X,
                                                 float* __restrict__ nrm) {
    __shared__ float s[256];
    int i = blockIdx.x, t = threadIdx.x;
    const float* row = X + (size_t)i * CC;
    float acc = 0.f;
#pragma unroll
    for (int j = 0; j < CC / 256; ++j) { float v = row[t + 256 * j]; acc += v * v; }
    s[t] = acc; __syncthreads();
    for (int d = 128; d > 0; d >>= 1) { if (t < d) s[t] += s[t + d]; __syncthreads(); }
    if (t == 0) nrm[i] = s[0];
}

// ---------------- split X -> bf16 hi/lo ----------------
__global__ __launch_bounds__(256) void k_split(const float* __restrict__ X,
                                               ushort_t* __restrict__ Xh,
                                               ushort_t* __restrict__ Xl) {
    int p = blockIdx.x * 256 + threadIdx.x;
    float4 v = *reinterpret_cast<const float4*>(&X[(size_t)p * 4]);
    float f[4] = { v.x, v.y, v.z, v.w };
    ushort4 H, L;
    unsigned short hh[4], ll[4];
#pragma unroll
    for (int i = 0; i < 4; ++i) {
        unsigned short hb = bf16_rne(f[i]);
        float hf = __uint_as_float((unsigned)hb << 16);
        hh[i] = hb;
        ll[i] = bf16_rne(f[i] - hf);
    }
    H.x = hh[0]; H.y = hh[1]; H.z = hh[2]; H.w = hh[3];
    L.x = ll[0]; L.y = ll[1]; L.z = ll[2]; L.w = ll[3];
    *reinterpret_cast<ushort4*>(&Xh[(size_t)p * 4]) = H;
    *reinterpret_cast<ushort4*>(&Xl[(size_t)p * 4]) = L;
}

// ---------------- coalesced transpose+split W1 [CC][HIDN] -> [HIDN][CC] hi/lo ----------------
__global__ __launch_bounds__(256) void k_wt(const float* __restrict__ W,
                                            ushort_t* __restrict__ Th,
                                            ushort_t* __restrict__ Tl) {
    __shared__ float s[32][33];
    int bx = blockIdx.x;              // n tile (16)
    int by = blockIdx.y;              // k tile (32)
    int tx = threadIdx.x & 31, ty = threadIdx.x >> 5;   // 32 x 8
#pragma unroll
    for (int rr = 0; rr < 4; ++rr) {
        int k = by * 32 + ty + rr * 8;
        s[ty + rr * 8][tx] = W[(size_t)k * HIDN + bx * 32 + tx];
    }
    __syncthreads();
#pragma unroll
    for (int rr = 0; rr < 4; ++rr) {
        int n = bx * 32 + ty + rr * 8;
        int k = by * 32 + tx;
        float x = s[tx][ty + rr * 8];
        unsigned short hb = bf16_rne(x);
        Th[(size_t)n * CC + k] = hb;
        Tl[(size_t)n * CC + k] = bf16_rne(x - __uint_as_float((unsigned)hb << 16));
    }
}

// ---------------- wbar[k] = sum_f W2[k][f] ----------------
__global__ __launch_bounds__(256) void k_w2bar(const float* __restrict__ W2,
                                               float* __restrict__ wbar) {
    int k = blockIdx.x * 256 + threadIdx.x;   // < HIDN
    const float* row = W2 + (size_t)k * FEATN;
    float s = 0.f;
#pragma unroll
    for (int f = 0; f < FEATN; f += 4) {
        float4 v = *reinterpret_cast<const float4*>(&row[f]);
        s += v.x + v.y + v.z + v.w;
    }
    wbar[k] = s;
}

// ---------------- bf16-split MFMA GEMM ----------------
// SYM: 1D grid of 528 upper-triangle blocks, XCD-chunk remapped for L2 reuse.
template <bool SYM, bool SCALE>
__global__ __launch_bounds__(256) void k_mm(const ushort_t* __restrict__ Ah,
                                            const ushort_t* __restrict__ Al,
                                            const ushort_t* __restrict__ Bth,
                                            const ushort_t* __restrict__ Btl,
                                            const float* __restrict__ rowscale,
                                            float* __restrict__ C, int ldc) {
    int bi, bj;
    if (SYM) {
        int b0 = (int)blockIdx.x;                  // 0..527
        int tri = (b0 & 7) * 66 + (b0 >> 3);       // XCD x gets contiguous ids
        float ft = (float)tri;
        int b = (int)floorf((65.0f - sqrtf(4225.0f - 8.0f * ft)) * 0.5f);
        while ((b + 1) * 32 - ((b + 1) * b) / 2 <= tri) ++b;
        while (b * 32 - (b * (b - 1)) / 2 > tri) --b;
        bi = b;
        bj = b + (tri - (b * 32 - (b * (b - 1)) / 2));
    } else {
        bi = blockIdx.y; bj = blockIdx.x;
    }
    __shared__ ushort_t lds[4][128][64];
    int t = threadIdx.x;
    int w = t >> 6, l = t & 63;
    int wr = (w >> 1) * 64, wc = (w & 1) * 64;

    f32x4 acc[4][4];
#pragma unroll
    for (int i = 0; i < 4; ++i)
#pragma unroll
        for (int j = 0; j < 4; ++j) acc[i][j] = (f32x4){0.f, 0.f, 0.f, 0.f};

    const ushort_t* src[4] = {
        Ah  + (size_t)bi * 128 * 1024,
        Al  + (size_t)bi * 128 * 1024,
        Bth + (size_t)bj * 128 * 1024,
        Btl + (size_t)bj * 128 * 1024
    };
    int rloc8 = l >> 3;
    int sp = l & 7;
    int sl = sp ^ rloc8;

    for (int kt = 0; kt < 16; ++kt) {
        int k0 = kt * 64;
#pragma unroll
        for (int q = 0; q < 4; ++q) {
#pragma unroll
            for (int s = 0; s < 4; ++s) {
                int rbase = (w * 4 + s) * 8;
                const ushort_t* g = src[q] + (size_t)(rbase + rloc8) * 1024 + k0 + sl * 8;
                async16(&lds[q][rbase][0], g);
            }
        }
        __syncthreads();
#pragma unroll
        for (int ks = 0; ks < 2; ++ks) {
            bf16x8 ah[4], al[4], bh[4], bl[4];
            int kg = ks * 4 + (l >> 4);
#pragma unroll
            for (int mi = 0; mi < 4; ++mi) {
                int row = wr + mi * 16 + (l & 15);
                int ph = kg ^ (row & 7);
                ah[mi] = *reinterpret_cast<const bf16x8*>(&lds[0][row][ph * 8]);
                al[mi] = *reinterpret_cast<const bf16x8*>(&lds[1][row][ph * 8]);
            }
#pragma unroll
            for (int nj = 0; nj < 4; ++nj) {
                int row = wc + nj * 16 + (l & 15);
                int ph = kg ^ (row & 7);
                bh[nj] = *reinterpret_cast<const bf16x8*>(&lds[2][row][ph * 8]);
                bl[nj] = *reinterpret_cast<const bf16x8*>(&lds[3][row][ph * 8]);
            }
#pragma unroll
            for (int mi = 0; mi < 4; ++mi)
#pragma unroll
                for (int nj = 0; nj < 4; ++nj) {
                    acc[mi][nj] = __builtin_amdgcn_mfma_f32_16x16x32_bf16(ah[mi], bh[nj], acc[mi][nj], 0, 0, 0);
                    acc[mi][nj] = __builtin_amdgcn_mfma_f32_16x16x32_bf16(ah[mi], bl[nj], acc[mi][nj], 0, 0, 0);
                    acc[mi][nj] = __builtin_amdgcn_mfma_f32_16x16x32_bf16(al[mi], bh[nj], acc[mi][nj], 0, 0, 0);
                }
        }
        __syncthreads();
    }
#pragma unroll
    for (int mi = 0; mi < 4; ++mi) {
#pragma unroll
        for (int r = 0; r < 4; ++r) {
            int rg = bi * 128 + wr + mi * 16 + (l >> 4) * 4 + r;
            float sc = SCALE ? rowscale[rg] : 1.0f;
#pragma unroll
            for (int nj = 0; nj < 4; ++nj) {
                int cg = bj * 128 + wc + nj * 16 + (l & 15);
                float v = acc[mi][nj][r] * sc;
                C[(size_t)rg * ldc + cg] = v;
                if (SYM && bi != bj) C[(size_t)cg * ldc + rg] = v;
            }
        }
    }
}

// ---------------- top-15: register keys, u64 shfl-min ----------------
__global__ __launch_bounds__(256) void k_topk(const float* __restrict__ G,
                                              const float* __restrict__ nrm,
                                              int* __restrict__ idx_out) {
    __shared__ unsigned long long wsm[4];
    int e = blockIdx.x, t = threadIdx.x;
    float ne = nrm[e];
    const float* Grow = G + (size_t)e * NN;
    unsigned long long key[16];
    unsigned long long my = ~0ull;
#pragma unroll
    for (int j = 0; j < 16; ++j) {
        int i = t + 256 * j;
        float v = fmaxf(ne + nrm[i] - 2.0f * Grow[i], 0.0f);
        unsigned long long k = ((unsigned long long)__float_as_uint(v) << 32) | (unsigned)i;
        key[j] = k;
        my = k < my ? k : my;
    }
    for (int r = 0; r < KMAX; ++r) {
        unsigned long long m = my;
#pragma unroll
        for (int d = 1; d < 64; d <<= 1) {
            unsigned long long o = __shfl_xor(m, d);
            m = o < m ? o : m;
        }
        if ((t & 63) == 0) wsm[t >> 6] = m;
        __syncthreads();
        unsigned long long b0 = wsm[0] < wsm[1] ? wsm[0] : wsm[1];
        unsigned long long b1 = wsm[2] < wsm[3] ? wsm[2] : wsm[3];
        unsigned long long bk = b0 < b1 ? b0 : b1;
        int win = (int)(unsigned)bk;
        if (t == 0) idx_out[e * 16 + r] = win;
        if (t == (win & 255)) {
            int jw = win >> 8;
#pragma unroll
            for (int jj = 0; jj < 16; ++jj) if (jj == jw) key[jj] = ~0ull;
            my = ~0ull;
#pragma unroll
            for (int jj = 0; jj < 16; ++jj) my = key[jj] < my ? key[jj] : my;
        }
        __syncthreads();
    }
}

// ---------------- degrees / CSR ----------------
__device__ __forceinline__ void decode_pair(int p, int& e, int& b, int& j) {
    e = p / KTOT;
    int q = p - e * KTOT;
    if (q < 5)       { b = 0; j = q; }
    else if (q < 15) { b = 1; j = q - 5; }
    else             { b = 2; j = q - 15; }
}

__global__ __launch_bounds__(256) void k_count(const int* __restrict__ idx, int* __restrict__ Dv) {
    int p = blockIdx.x * 256 + threadIdx.x;
    int e, b, j; decode_pair(p, e, b, j);
    (void)b;
    atomicAdd(&Dv[idx[e * 16 + j]], 1);
}

__global__ __launch_bounds__(256) void k_dv(const int* __restrict__ Dv, float* __restrict__ dvv) {
    int i = blockIdx.x * 256 + threadIdx.x;
    int d = Dv[i];
    dvv[i] = d > 0 ? 1.0f / sqrtf((float)d) : 0.0f;
}

__global__ __launch_bounds__(1024) void k_scan(const int* __restrict__ Dv,
                                               int* __restrict__ offs,
                                               int* __restrict__ cur,
                                               int* __restrict__ chunkoffs,
                                               int* __restrict__ nchunks) {
    __shared__ int s[1024];
    int t = threadIdx.x;
    int v[4]; int sum = 0;
#pragma unroll
    for (int j = 0; j < 4; ++j) { v[j] = Dv[t * 4 + j]; sum += v[j]; }
    s[t] = sum; __syncthreads();
    for (int d = 1; d < 1024; d <<= 1) {
        int add = (t >= d) ? s[t - d] : 0;
        __syncthreads();
        s[t] += add;
        __syncthreads();
    }
    int run = s[t] - sum;
#pragma unroll
    for (int j = 0; j < 4; ++j) { offs[t * 4 + j] = run; cur[t * 4 + j] = run; run += v[j]; }
    if (t == 1023) offs[NN] = run;
    __syncthreads();
    int c[4]; int csum = 0;
#pragma unroll
    for (int j = 0; j < 4; ++j) { c[j] = (v[j] + CH - 1) / CH; csum += c[j]; }
    s[t] = csum; __syncthreads();
    for (int d = 1; d < 1024; d <<= 1) {
        int add = (t >= d) ? s[t - d] : 0;
        __syncthreads();
        s[t] += add;
        __syncthreads();
    }
    int crun = s[t] - csum;
#pragma unroll
    for (int j = 0; j < 4; ++j) { chunkoffs[t * 4 + j] = crun; crun += c[j]; }
    if (t == 1023) { chunkoffs[NN] = crun; *nchunks = crun; }
}

__global__ __launch_bounds__(256) void k_fill(const int* __restrict__ idx,
                                              int* __restrict__ cur,
                                              int* __restrict__ adj) {
    int p = blockIdx.x * 256 + threadIdx.x;
    int e, b, j; decode_pair(p, e, b, j);
    int i = idx[e * 16 + j];
    int eg = b * NN + e;
    int pos = atomicAdd(&cur[i], 1);
    adj[pos] = eg;
}

__global__ __launch_bounds__(256) void k_tasks(const int* __restrict__ chunkoffs,
                                               int* __restrict__ task_node) {
    int i = blockIdx.x * 256 + threadIdx.x;
    int c0 = chunkoffs[i], c1 = chunkoffs[i + 1];
    for (int c = c0; c < c1; ++c) task_node[c] = i;
}

// ---------------- ze_e = (1/k) sum_{j in S_e} dv_j ----------------
__global__ __launch_bounds__(256) void k_ze(const int* __restrict__ idx,
                                            const float* __restrict__ dvv,
                                            float* __restrict__ ze) {
    int eg = blockIdx.x * 256 + threadIdx.x;   // < NE
    int b = eg >> 12, e = eg & (NN - 1);
    int kb = (b == 0) ? 5 : (b == 1) ? 10 : 15;
    const int* row = idx + e * 16;
    float s = 0.f;
    for (int j = 0; j < kb; ++j) s += dvv[row[j]];
    ze[eg] = s / (float)kb;
}

// ---------------- a_raw[i] = sum_{e ni i} ze_e (scatter) ----------------
__global__ __launch_bounds__(256) void k_ascat(const int* __restrict__ idx,
                                               const float* __restrict__ ze,
                                               float* __restrict__ a) {
    int p = blockIdx.x * 256 + threadIdx.x;
    int e, b, j; decode_pair(p, e, b, j);
    atomicAdd(&a[idx[e * 16 + j]], ze[b * NN + e]);
}

// ---------------- incremental hyperedge gather: all 3 k-blocks in one pass ----------------
__global__ __launch_bounds__(256) void k_edge3(const int* __restrict__ idx,
                                               const float* __restrict__ ts,
                                               float* __restrict__ m) {
    int p = blockIdx.x * 256 + threadIdx.x;    // NN*128
    int e = p >> 7;
    int c4 = (p & 127) * 4;
    const int* row = idx + e * 16;
    float4 acc = make_float4(0.f, 0.f, 0.f, 0.f);
#pragma unroll
    for (int j = 0; j < 5; ++j) {
        float4 v = *reinterpret_cast<const float4*>(&ts[(size_t)row[j] * HIDN + c4]);
        acc.x += v.x; acc.y += v.y; acc.z += v.z; acc.w += v.w;
    }
    *reinterpret_cast<float4*>(&m[(size_t)e * HIDN + c4]) =
        make_float4(acc.x * 0.2f, acc.y * 0.2f, acc.z * 0.2f, acc.w * 0.2f);
#pragma unroll
    for (int j = 5; j < 10; ++j) {
        float4 v = *reinterpret_cast<const float4*>(&ts[(size_t)row[j] * HIDN + c4]);
        acc.x += v.x; acc.y += v.y; acc.z += v.z; acc.w += v.w;
    }
    *reinterpret_cast<float4*>(&m[(size_t)(NN + e) * HIDN + c4]) =
        make_float4(acc.x * 0.1f, acc.y * 0.1f, acc.z * 0.1f, acc.w * 0.1f);
#pragma unroll
    for (int j = 10; j < 15; ++j) {
        float4 v = *reinterpret_cast<const float4*>(&ts[(size_t)row[j] * HIDN + c4]);
        acc.x += v.x; acc.y += v.y; acc.z += v.z; acc.w += v.w;
    }
    constexpr float d15 = 1.0f / 15.0f;
    *reinterpret_cast<float4*>(&m[(size_t)(2 * NN + e) * HIDN + c4]) =
        make_float4(acc.x * d15, acc.y * d15, acc.z * d15, acc.w * d15);
}

// ---------------- chunked node gather (F=512) ----------------
__global__ __launch_bounds__(256) void k_chunk(const int* __restrict__ offs,
                                               const int* __restrict__ chunkoffs,
                                               const int* __restrict__ task_node,
                                               const int* __restrict__ nchunks,
                                               const int* __restrict__ adj,
                                               const float* __restrict__ m,
                                               float* __restrict__ partial) {
    int task = blockIdx.x * 2 + threadIdx.x / 128;
    if (task >= *nchunks) return;
    int c4 = (threadIdx.x % 128) * 4;
    int i = task_node[task];
    int ck = task - chunkoffs[i];
    int q0 = offs[i] + ck * CH;
    int n = offs[i + 1] - q0;
    n = n < CH ? n : CH;
    int e[CH];
#pragma unroll
    for (int j = 0; j < CH; ++j) e[j] = (j < n) ? adj[q0 + j] : -1;
    float4 acc = make_float4(0.f, 0.f, 0.f, 0.f);
#pragma unroll
    for (int j = 0; j < CH; ++j) {
        if (e[j] >= 0) {
            float4 v = *reinterpret_cast<const float4*>(&m[(size_t)e[j] * HIDN + c4]);
            acc.x += v.x; acc.y += v.y; acc.z += v.z; acc.w += v.w;
        }
    }
    *reinterpret_cast<float4*>(&partial[(size_t)task * HIDN + c4]) = acc;
}

// ---------------- fused combine: g[i] = dv_i * a_raw_i * (relu(dv_i * sum partials) . wbar) ----------------
__global__ __launch_bounds__(256) void k_comb2(const int* __restrict__ chunkoffs,
                                               const float* __restrict__ dvv,
                                               const float* __restrict__ a,
                                               const float* __restrict__ wbar,
                                               const float* __restrict__ partial,
                                               float* __restrict__ g) {
    __shared__ float s[256];
    int p = blockIdx.x * 256 + threadIdx.x;    // NN*128
    int i = p >> 7;
    int c4 = (p & 127) * 4;
    int c0 = chunkoffs[i], c1 = chunkoffs[i + 1];
    float4 acc = make_float4(0.f, 0.f, 0.f, 0.f);
    for (int c = c0; c < c1; ++c) {
        float4 v = *reinterpret_cast<const float4*>(&partial[(size_t)c * HIDN + c4]);
        acc.x += v.x; acc.y += v.y; acc.z += v.z; acc.w += v.w;
    }
    float dv = dvv[i];
    float4 wv = *reinterpret_cast<const float4*>(&wbar[c4]);
    float val = fmaxf(acc.x * dv, 0.f) * wv.x + fmaxf(acc.y * dv, 0.f) * wv.y +
                fmaxf(acc.z * dv, 0.f) * wv.z + fmaxf(acc.w * dv, 0.f) * wv.w;
    int t = threadIdx.x;
    s[t] = val; __syncthreads();
    for (int d = 64; d > 0; d >>= 1) {
        if ((t & 127) < d) s[t] += s[t + d];
        __syncthreads();
    }
    if ((t & 127) == 0) g[i] = s[t] * dv * a[i];
}

// ---------------- final reductions ----------------
__global__ __launch_bounds__(1024) void k_yred(const float* __restrict__ g,
                                               float* __restrict__ ys, int slot) {
    __shared__ float s[1024];
    int t = threadIdx.x;
    s[t] = g[t] + g[t + 1024] + g[t + 2048] + g[t + 3072];
    __syncthreads();
    for (int d = 512; d > 0; d >>= 1) { if (t < d) s[t] += s[t + d]; __syncthreads(); }
    if (t == 0) ys[slot] = s[0];
}

__global__ void k_fin(const float* __restrict__ ys, float* __restrict__ out) {
    float y0 = ys[0] / (float)NN, y1 = ys[1] / (float)NN;
    out[0] = 1.0f / (1.0f + expf(-(y0 - y1)));
    out[1] = y0;
    out[2] = y1;
}

// ---------------- launch ----------------
extern "C" void kernel_launch(void* const* d_in, const int* in_sizes, int n_in,
                              void* d_out, int out_size, void* d_ws, size_t ws_size,
                              hipStream_t stream) {
    const float* fts[2] = { (const float*)d_in[0], (const float*)d_in[1] };
    const float* W1 = (const float*)d_in[2];
    const float* W2 = (const float*)d_in[3];
    float* out = (float*)d_out;

    char* p = (char*)d_ws;
    auto alloc = [&](size_t b) { char* r = p; p += (b + 255) & ~(size_t)255; return r; };
    float* G    = (float*)alloc((size_t)NN * NN * 4);        // 64 MB; reused as chunk-partial buffer
    float* nrm  = (float*)alloc((size_t)NN * 4);
    int*   idx  = (int*)  alloc((size_t)NN * 16 * 4);
    int*   Dv   = (int*)  alloc((size_t)NN * 4);
    float* dvv  = (float*)alloc((size_t)NN * 4);
    int*   offs = (int*)  alloc((size_t)(NN + 1) * 4);
    int*   cur  = (int*)  alloc((size_t)NN * 4);
    int*   coffs= (int*)  alloc((size_t)(NN + 1) * 4);
    int*   nch  = (int*)  alloc(4);
    int*   tnode= (int*)  alloc((size_t)MAXCH * 4);
    int*   adj  = (int*)  alloc((size_t)NN * KTOT * 4);
    float* t1   = (float*)alloc((size_t)NN * HIDN * 4);
    float* m    = (float*)alloc((size_t)NE * HIDN * 4);      // 25 MB; Xh/Xl alias (consumed first)
    ushort_t* W1Th = (ushort_t*)alloc((size_t)HIDN * CC * 2);
    ushort_t* W1Tl = (ushort_t*)alloc((size_t)HIDN * CC * 2);
    float* wbar = (float*)alloc((size_t)HIDN * 4);
    float* ze   = (float*)alloc((size_t)NE * 4);
    float* a    = (float*)alloc((size_t)NN * 4);
    float* g    = (float*)alloc((size_t)NN * 4);
    float* ys   = (float*)alloc(2 * 4);

    ushort_t* Xh = (ushort_t*)m;
    ushort_t* Xl = Xh + (size_t)NN * CC;
    float* partial = G;   // chunk partials alias G (free after k_topk)

    k_wt<<<dim3(HIDN / 32, CC / 32), 256, 0, stream>>>(W1, W1Th, W1Tl);
    k_w2bar<<<HIDN / 256, 256, 0, stream>>>(W2, wbar);

    for (int s = 0; s < 2; ++s) {
        const float* X = fts[s];
        k_rownorm<<<NN, 256, 0, stream>>>(X, nrm);
        k_split<<<NN * CC / 4 / 256, 256, 0, stream>>>(X, Xh, Xl);
        k_mm<true, false><<<528, 256, 0, stream>>>(Xh, Xl, Xh, Xl, nullptr, G, NN);
        k_topk<<<NN, 256, 0, stream>>>(G, nrm, idx);
        hipMemsetAsync(Dv, 0, NN * 4, stream);
        k_count<<<NN * KTOT / 256, 256, 0, stream>>>(idx, Dv);
        k_dv<<<NN / 256, 256, 0, stream>>>(Dv, dvv);
        k_scan<<<1, 1024, 0, stream>>>(Dv, offs, cur, coffs, nch);
        k_fill<<<NN * KTOT / 256, 256, 0, stream>>>(idx, cur, adj);
        k_tasks<<<NN / 256, 256, 0, stream>>>(coffs, tnode);
        // a = A 1 (sparse scalar passes)
        k_ze<<<NE / 256, 256, 0, stream>>>(idx, dvv, ze);
        hipMemsetAsync(a, 0, NN * 4, stream);
        k_ascat<<<NN * KTOT / 256, 256, 0, stream>>>(idx, ze, a);
        // conv1: t1 = dv * (X @ W1); m (all 3 k-blocks); chunked node gather
        k_mm<false, true><<<dim3(HIDN / 128, NN / 128), 256, 0, stream>>>(Xh, Xl, W1Th, W1Tl, dvv, t1, HIDN);
        k_edge3<<<NN * 128 / 256, 256, 0, stream>>>(idx, t1, m);
        k_chunk<<<MAXCH / 2, 256, 0, stream>>>(offs, coffs, tnode, nch, adj, m, partial);
        // layer-2 collapsed: g[i] = a_i * (relu(u1_i) . wbar); y = sum(g)/N
        k_comb2<<<NN * 128 / 256, 256, 0, stream>>>(coffs, dvv, a, wbar, partial, g);
        k_yred<<<1, 1024, 0, stream>>>(g, ys, s);
    }
    k_fin<<<1, 1, 0, stream>>>(ys, out);
}

// Round 6
// 691.390 us; speedup vs baseline: 5.5607x; 1.1155x over previous
//
#include <hip/hip_runtime.h>
#include <math.h>

// DiffRankNet: HGNN forward on MI355X.
// R5: (1) Gram supertiled 4x4-block L2-resident schedule per XCD;
//     (2) mirror write via LDS transpose (coalesced, kills write-allocate);
//     (3) t1/m in bf16 (smooth path only; selection stays f32).
// out = [sigmoid(y0-y1), y0, y1]

#define NN   4096
#define CC   1024
#define HIDN 512
#define FEATN 128
#define NE   12288
#define KTOT 30
#define KMAX 15
#define CH   16
#define MAXCH (NN + NN * KTOT / CH)

typedef __attribute__((ext_vector_type(8))) short bf16x8;
typedef __attribute__((ext_vector_type(4))) float f32x4;
typedef unsigned short ushort_t;

__device__ __forceinline__ unsigned short bf16_rne(float x) {
    unsigned u = __float_as_uint(x);
    unsigned r = (u + 0x7FFFu + ((u >> 16) & 1u)) >> 16;
    return (unsigned short)r;
}
__device__ __forceinline__ float bf16_lo(unsigned u) { return __uint_as_float(u << 16); }
__device__ __forceinline__ float bf16_hi(unsigned u) { return __uint_as_float(u & 0xFFFF0000u); }
__device__ __forceinline__ unsigned packbf(float a, float b) {
    return (unsigned)bf16_rne(a) | ((unsigned)bf16_rne(b) << 16);
}

__device__ __forceinline__ void async16(void* lds, const void* g) {
    __builtin_amdgcn_global_load_lds((const __attribute__((address_space(1))) unsigned int*)g,
                                     (__attribute__((address_space(3))) unsigned int*)lds, 16, 0, 0);
}

// ---------------- row squared norms ----------------
__global__ __launch_bounds__(256) void k_rownorm(const float* __restrict__ X,
                                                 float* __restrict__ nrm) {
    __shared__ float s[256];
    int i = blockIdx.x, t = threadIdx.x;
    const float* row = X + (size_t)i * CC;
    float acc = 0.f;
#pragma unroll
    for (int j = 0; j < CC / 256; ++j) { float v = row[t + 256 * j]; acc += v * v; }
    s[t] = acc; __syncthreads();
    for (int d = 128; d > 0; d >>= 1) { if (t < d) s[t] += s[t + d]; __syncthreads(); }
    if (t == 0) nrm[i] = s[0];
}

// ---------------- split X -> bf16 hi/lo ----------------
__global__ __launch_bounds__(256) void k_split(const float* __restrict__ X,
                                               ushort_t* __restrict__ Xh,
                                               ushort_t* __restrict__ Xl) {
    int p = blockIdx.x * 256 + threadIdx.x;
    float4 v = *reinterpret_cast<const float4*>(&X[(size_t)p * 4]);
    float f[4] = { v.x, v.y, v.z, v.w };
    ushort4 H, L;
    unsigned short hh[4], ll[4];
#pragma unroll
    for (int i = 0; i < 4; ++i) {
        unsigned short hb = bf16_rne(f[i]);
        float hf = __uint_as_float((unsigned)hb << 16);
        hh[i] = hb;
        ll[i] = bf16_rne(f[i] - hf);
    }
    H.x = hh[0]; H.y = hh[1]; H.z = hh[2]; H.w = hh[3];
    L.x = ll[0]; L.y = ll[1]; L.z = ll[2]; L.w = ll[3];
    *reinterpret_cast<ushort4*>(&Xh[(size_t)p * 4]) = H;
    *reinterpret_cast<ushort4*>(&Xl[(size_t)p * 4]) = L;
}

// ---------------- coalesced transpose+split W1 ----------------
__global__ __launch_bounds__(256) void k_wt(const float* __restrict__ W,
                                            ushort_t* __restrict__ Th,
                                            ushort_t* __restrict__ Tl) {
    __shared__ float s[32][33];
    int bx = blockIdx.x, by = blockIdx.y;
    int tx = threadIdx.x & 31, ty = threadIdx.x >> 5;
#pragma unroll
    for (int rr = 0; rr < 4; ++rr) {
        int k = by * 32 + ty + rr * 8;
        s[ty + rr * 8][tx] = W[(size_t)k * HIDN + bx * 32 + tx];
    }
    __syncthreads();
#pragma unroll
    for (int rr = 0; rr < 4; ++rr) {
        int n = bx * 32 + ty + rr * 8;
        int k = by * 32 + tx;
        float x = s[tx][ty + rr * 8];
        unsigned short hb = bf16_rne(x);
        Th[(size_t)n * CC + k] = hb;
        Tl[(size_t)n * CC + k] = bf16_rne(x - __uint_as_float((unsigned)hb << 16));
    }
}

// ---------------- wbar[k] = sum_f W2[k][f] ----------------
__global__ __launch_bounds__(256) void k_w2bar(const float* __restrict__ W2,
                                               float* __restrict__ wbar) {
    int k = blockIdx.x * 256 + threadIdx.x;
    const float* row = W2 + (size_t)k * FEATN;
    float s = 0.f;
#pragma unroll
    for (int f = 0; f < FEATN; f += 4) {
        float4 v = *reinterpret_cast<const float4*>(&row[f]);
        s += v.x + v.y + v.z + v.w;
    }
    wbar[k] = s;
}

// ---------------- bf16-split MFMA GEMM ----------------
// SYM: 528 triangle blocks, supertiled 4x4 (L2-resident panels), XCD-contiguous.
// OUTB: write bf16 output (t1) with rowscale.
template <bool SYM, bool SCALE, bool OUTB>
__global__ __launch_bounds__(256) void k_mm(const ushort_t* __restrict__ Ah,
                                            const ushort_t* __restrict__ Al,
                                            const ushort_t* __restrict__ Bth,
                                            const ushort_t* __restrict__ Btl,
                                            const float* __restrict__ rowscale,
                                            float* __restrict__ C,
                                            ushort_t* __restrict__ Cb, int ldc) {
    int bi, bj;
    if (SYM) {
        int b0 = (int)blockIdx.x;                  // 528
        int L = (b0 & 7) * 66 + (b0 >> 3);         // XCD-contiguous stream
        // supertile decode: for si 0..7: [diag si (10)], [off (si,sj) sj>si (16 each)]
        int rem = L, si = 0;
        for (; si < 8; ++si) {
            int grp = 10 + (7 - si) * 16;
            if (rem < grp) break;
            rem -= grp;
        }
        int sj, u, v;
        if (rem < 10) {
            int uu = 0, r2 = rem;
            while (r2 >= 4 - uu) { r2 -= 4 - uu; ++uu; }
            u = uu; v = uu + r2; sj = si;
        } else {
            int r2 = rem - 10;
            sj = si + 1 + (r2 >> 4);
            int w2 = r2 & 15;
            u = w2 >> 2; v = w2 & 3;
        }
        bi = si * 4 + u; bj = sj * 4 + v;
    } else {
        bi = blockIdx.y; bj = blockIdx.x;
    }
    __shared__ ushort_t lds[4][128][64];   // 64 KB
    int t = threadIdx.x;
    int w = t >> 6, l = t & 63;
    int wr = (w >> 1) * 64, wc = (w & 1) * 64;

    f32x4 acc[4][4];
#pragma unroll
    for (int i = 0; i < 4; ++i)
#pragma unroll
        for (int j = 0; j < 4; ++j) acc[i][j] = (f32x4){0.f, 0.f, 0.f, 0.f};

    const ushort_t* src[4] = {
        Ah  + (size_t)bi * 128 * 1024,
        Al  + (size_t)bi * 128 * 1024,
        Bth + (size_t)bj * 128 * 1024,
        Btl + (size_t)bj * 128 * 1024
    };
    int rloc8 = l >> 3;
    int sp = l & 7;
    int sl = sp ^ rloc8;

    for (int kt = 0; kt < 16; ++kt) {
        int k0 = kt * 64;
#pragma unroll
        for (int q = 0; q < 4; ++q) {
#pragma unroll
            for (int s = 0; s < 4; ++s) {
                int rbase = (w * 4 + s) * 8;
                const ushort_t* g = src[q] + (size_t)(rbase + rloc8) * 1024 + k0 + sl * 8;
                async16(&lds[q][rbase][0], g);
            }
        }
        __syncthreads();
#pragma unroll
        for (int ks = 0; ks < 2; ++ks) {
            bf16x8 ah[4], al[4], bh[4], bl[4];
            int kg = ks * 4 + (l >> 4);
#pragma unroll
            for (int mi = 0; mi < 4; ++mi) {
                int row = wr + mi * 16 + (l & 15);
                int ph = kg ^ (row & 7);
                ah[mi] = *reinterpret_cast<const bf16x8*>(&lds[0][row][ph * 8]);
                al[mi] = *reinterpret_cast<const bf16x8*>(&lds[1][row][ph * 8]);
            }
#pragma unroll
            for (int nj = 0; nj < 4; ++nj) {
                int row = wc + nj * 16 + (l & 15);
                int ph = kg ^ (row & 7);
                bh[nj] = *reinterpret_cast<const bf16x8*>(&lds[2][row][ph * 8]);
                bl[nj] = *reinterpret_cast<const bf16x8*>(&lds[3][row][ph * 8]);
            }
#pragma unroll
            for (int mi = 0; mi < 4; ++mi)
#pragma unroll
                for (int nj = 0; nj < 4; ++nj) {
                    acc[mi][nj] = __builtin_amdgcn_mfma_f32_16x16x32_bf16(ah[mi], bh[nj], acc[mi][nj], 0, 0, 0);
                    acc[mi][nj] = __builtin_amdgcn_mfma_f32_16x16x32_bf16(ah[mi], bl[nj], acc[mi][nj], 0, 0, 0);
                    acc[mi][nj] = __builtin_amdgcn_mfma_f32_16x16x32_bf16(al[mi], bh[nj], acc[mi][nj], 0, 0, 0);
                }
        }
        __syncthreads();
    }
    if (!OUTB) {
        // direct (bi,bj) tile write
#pragma unroll
        for (int mi = 0; mi < 4; ++mi) {
#pragma unroll
            for (int r = 0; r < 4; ++r) {
                int rg = bi * 128 + wr + mi * 16 + (l >> 4) * 4 + r;
                float sc = SCALE ? rowscale[rg] : 1.0f;
#pragma unroll
                for (int nj = 0; nj < 4; ++nj) {
                    int cg = bj * 128 + wc + nj * 16 + (l & 15);
                    C[(size_t)rg * ldc + cg] = acc[mi][nj][r] * sc;
                }
            }
        }
        if (SYM && bi != bj) {
            // transpose in LDS (reuse staging buffer), then coalesced mirror write
            float* fl = (float*)lds;   // [128][128] f32 = 64 KB
#pragma unroll
            for (int mi = 0; mi < 4; ++mi)
#pragma unroll
                for (int r = 0; r < 4; ++r) {
                    int rl = wr + mi * 16 + (l >> 4) * 4 + r;
#pragma unroll
                    for (int nj = 0; nj < 4; ++nj) {
                        int cl = wc + nj * 16 + (l & 15);
                        fl[cl * 128 + rl] = acc[mi][nj][r];
                    }
                }
            __syncthreads();
            int row = t >> 1, co = (t & 1) * 64;
            const float4* srow = reinterpret_cast<const float4*>(&fl[row * 128 + co]);
            float4* dst = reinterpret_cast<float4*>(&C[(size_t)(bj * 128 + row) * ldc + bi * 128 + co]);
#pragma unroll
            for (int q = 0; q < 16; ++q) dst[q] = srow[q];
        }
    } else {
#pragma unroll
        for (int mi = 0; mi < 4; ++mi) {
#pragma unroll
            for (int r = 0; r < 4; ++r) {
                int rg = bi * 128 + wr + mi * 16 + (l >> 4) * 4 + r;
                float sc = SCALE ? rowscale[rg] : 1.0f;
#pragma unroll
                for (int nj = 0; nj < 4; ++nj) {
                    int cg = bj * 128 + wc + nj * 16 + (l & 15);
                    Cb[(size_t)rg * ldc + cg] = bf16_rne(acc[mi][nj][r] * sc);
                }
            }
        }
    }
}

// ---------------- top-15: register keys, u64 shfl-min ----------------
__global__ __launch_bounds__(256) void k_topk(const float* __restrict__ G,
                                              const float* __restrict__ nrm,
                                              int* __restrict__ idx_out) {
    __shared__ unsigned long long wsm[4];
    int e = blockIdx.x, t = threadIdx.x;
    float ne = nrm[e];
    const float* Grow = G + (size_t)e * NN;
    unsigned long long key[16];
    unsigned long long my = ~0ull;
#pragma unroll
    for (int j = 0; j < 16; ++j) {
        int i = t + 256 * j;
        float v = fmaxf(ne + nrm[i] - 2.0f * Grow[i], 0.0f);
        unsigned long long k = ((unsigned long long)__float_as_uint(v) << 32) | (unsigned)i;
        key[j] = k;
        my = k < my ? k : my;
    }
    for (int r = 0; r < KMAX; ++r) {
        unsigned long long m = my;
#pragma unroll
        for (int d = 1; d < 64; d <<= 1) {
            unsigned long long o = __shfl_xor(m, d);
            m = o < m ? o : m;
        }
        if ((t & 63) == 0) wsm[t >> 6] = m;
        __syncthreads();
        unsigned long long b0 = wsm[0] < wsm[1] ? wsm[0] : wsm[1];
        unsigned long long b1 = wsm[2] < wsm[3] ? wsm[2] : wsm[3];
        unsigned long long bk = b0 < b1 ? b0 : b1;
        int win = (int)(unsigned)bk;
        if (t == 0) idx_out[e * 16 + r] = win;
        if (t == (win & 255)) {
            int jw = win >> 8;
#pragma unroll
            for (int jj = 0; jj < 16; ++jj) if (jj == jw) key[jj] = ~0ull;
            my = ~0ull;
#pragma unroll
            for (int jj = 0; jj < 16; ++jj) my = key[jj] < my ? key[jj] : my;
        }
        __syncthreads();
    }
}

// ---------------- degrees / CSR ----------------
__device__ __forceinline__ void decode_pair(int p, int& e, int& b, int& j) {
    e = p / KTOT;
    int q = p - e * KTOT;
    if (q < 5)       { b = 0; j = q; }
    else if (q < 15) { b = 1; j = q - 5; }
    else             { b = 2; j = q - 15; }
}

__global__ __launch_bounds__(256) void k_count(const int* __restrict__ idx, int* __restrict__ Dv) {
    int p = blockIdx.x * 256 + threadIdx.x;
    int e, b, j; decode_pair(p, e, b, j);
    (void)b;
    atomicAdd(&Dv[idx[e * 16 + j]], 1);
}

__global__ __launch_bounds__(256) void k_dv(const int* __restrict__ Dv, float* __restrict__ dvv) {
    int i = blockIdx.x * 256 + threadIdx.x;
    int d = Dv[i];
    dvv[i] = d > 0 ? 1.0f / sqrtf((float)d) : 0.0f;
}

__global__ __launch_bounds__(1024) void k_scan(const int* __restrict__ Dv,
                                               int* __restrict__ offs,
                                               int* __restrict__ cur,
                                               int* __restrict__ chunkoffs,
                                               int* __restrict__ nchunks) {
    __shared__ int s[1024];
    int t = threadIdx.x;
    int v[4]; int sum = 0;
#pragma unroll
    for (int j = 0; j < 4; ++j) { v[j] = Dv[t * 4 + j]; sum += v[j]; }
    s[t] = sum; __syncthreads();
    for (int d = 1; d < 1024; d <<= 1) {
        int add = (t >= d) ? s[t - d] : 0;
        __syncthreads();
        s[t] += add;
        __syncthreads();
    }
    int run = s[t] - sum;
#pragma unroll
    for (int j = 0; j < 4; ++j) { offs[t * 4 + j] = run; cur[t * 4 + j] = run; run += v[j]; }
    if (t == 1023) offs[NN] = run;
    __syncthreads();
    int c[4]; int csum = 0;
#pragma unroll
    for (int j = 0; j < 4; ++j) { c[j] = (v[j] + CH - 1) / CH; csum += c[j]; }
    s[t] = csum; __syncthreads();
    for (int d = 1; d < 1024; d <<= 1) {
        int add = (t >= d) ? s[t - d] : 0;
        __syncthreads();
        s[t] += add;
        __syncthreads();
    }
    int crun = s[t] - csum;
#pragma unroll
    for (int j = 0; j < 4; ++j) { chunkoffs[t * 4 + j] = crun; crun += c[j]; }
    if (t == 1023) { chunkoffs[NN] = crun; *nchunks = crun; }
}

__global__ __launch_bounds__(256) void k_fill(const int* __restrict__ idx,
                                              int* __restrict__ cur,
                                              int* __restrict__ adj) {
    int p = blockIdx.x * 256 + threadIdx.x;
    int e, b, j; decode_pair(p, e, b, j);
    int i = idx[e * 16 + j];
    int eg = b * NN + e;
    int pos = atomicAdd(&cur[i], 1);
    adj[pos] = eg;
}

__global__ __launch_bounds__(256) void k_tasks(const int* __restrict__ chunkoffs,
                                               int* __restrict__ task_node) {
    int i = blockIdx.x * 256 + threadIdx.x;
    int c0 = chunkoffs[i], c1 = chunkoffs[i + 1];
    for (int c = c0; c < c1; ++c) task_node[c] = i;
}

// ---------------- ze / a = A 1 ----------------
__global__ __launch_bounds__(256) void k_ze(const int* __restrict__ idx,
                                            const float* __restrict__ dvv,
                                            float* __restrict__ ze) {
    int eg = blockIdx.x * 256 + threadIdx.x;
    int b = eg >> 12, e = eg & (NN - 1);
    int kb = (b == 0) ? 5 : (b == 1) ? 10 : 15;
    const int* row = idx + e * 16;
    float s = 0.f;
    for (int j = 0; j < kb; ++j) s += dvv[row[j]];
    ze[eg] = s / (float)kb;
}

__global__ __launch_bounds__(256) void k_ascat(const int* __restrict__ idx,
                                               const float* __restrict__ ze,
                                               float* __restrict__ a) {
    int p = blockIdx.x * 256 + threadIdx.x;
    int e, b, j; decode_pair(p, e, b, j);
    atomicAdd(&a[idx[e * 16 + j]], ze[b * NN + e]);
}

// ---------------- incremental edge gather (bf16 in, bf16 out) ----------------
__global__ __launch_bounds__(256) void k_edge3(const int* __restrict__ idx,
                                               const ushort_t* __restrict__ t1b,
                                               ushort_t* __restrict__ m) {
    int p = blockIdx.x * 256 + threadIdx.x;    // NN*64
    int e = p >> 6;
    int c8 = (p & 63) * 8;
    const int* row = idx + e * 16;
    float acc[8] = {};
    auto addrow = [&](int j) {
        uint4 raw = *reinterpret_cast<const uint4*>(&t1b[(size_t)row[j] * HIDN + c8]);
        acc[0] += bf16_lo(raw.x); acc[1] += bf16_hi(raw.x);
        acc[2] += bf16_lo(raw.y); acc[3] += bf16_hi(raw.y);
        acc[4] += bf16_lo(raw.z); acc[5] += bf16_hi(raw.z);
        acc[6] += bf16_lo(raw.w); acc[7] += bf16_hi(raw.w);
    };
    auto store = [&](size_t eg, float sc) {
        uint4 o;
        o.x = packbf(acc[0] * sc, acc[1] * sc);
        o.y = packbf(acc[2] * sc, acc[3] * sc);
        o.z = packbf(acc[4] * sc, acc[5] * sc);
        o.w = packbf(acc[6] * sc, acc[7] * sc);
        *reinterpret_cast<uint4*>(&m[eg * HIDN + c8]) = o;
    };
#pragma unroll
    for (int j = 0; j < 5; ++j) addrow(j);
    store((size_t)e, 0.2f);
#pragma unroll
    for (int j = 5; j < 10; ++j) addrow(j);
    store((size_t)(NN + e), 0.1f);
#pragma unroll
    for (int j = 10; j < 15; ++j) addrow(j);
    store((size_t)(2 * NN + e), 1.0f / 15.0f);
}

// ---------------- chunked node gather (bf16 m -> f32 partial) ----------------
__global__ __launch_bounds__(256) void k_chunk(const int* __restrict__ offs,
                                               const int* __restrict__ chunkoffs,
                                               const int* __restrict__ task_node,
                                               const int* __restrict__ nchunks,
                                               const int* __restrict__ adj,
                                               const ushort_t* __restrict__ m,
                                               float* __restrict__ partial) {
    int task = blockIdx.x * 4 + threadIdx.x / 64;
    if (task >= *nchunks) return;
    int c8 = (threadIdx.x & 63) * 8;
    int i = task_node[task];
    int ck = task - chunkoffs[i];
    int q0 = offs[i] + ck * CH;
    int n = offs[i + 1] - q0;
    n = n < CH ? n : CH;
    int e[CH];
#pragma unroll
    for (int j = 0; j < CH; ++j) e[j] = (j < n) ? adj[q0 + j] : -1;
    float acc[8] = {};
#pragma unroll
    for (int j = 0; j < CH; ++j) {
        if (e[j] >= 0) {
            uint4 raw = *reinterpret_cast<const uint4*>(&m[(size_t)e[j] * HIDN + c8]);
            acc[0] += bf16_lo(raw.x); acc[1] += bf16_hi(raw.x);
            acc[2] += bf16_lo(raw.y); acc[3] += bf16_hi(raw.y);
            acc[4] += bf16_lo(raw.z); acc[5] += bf16_hi(raw.z);
            acc[6] += bf16_lo(raw.w); acc[7] += bf16_hi(raw.w);
        }
    }
    float* o = &partial[(size_t)task * HIDN + c8];
    *reinterpret_cast<float4*>(o)     = make_float4(acc[0], acc[1], acc[2], acc[3]);
    *reinterpret_cast<float4*>(o + 4) = make_float4(acc[4], acc[5], acc[6], acc[7]);
}

// ---------------- fused combine: g[i] = dv_i * a_i * (relu(dv_i * sum partials) . wbar) ----------------
__global__ __launch_bounds__(256) void k_comb2(const int* __restrict__ chunkoffs,
                                               const float* __restrict__ dvv,
                                               const float* __restrict__ a,
                                               const float* __restrict__ wbar,
                                               const float* __restrict__ partial,
                                               float* __restrict__ g) {
    __shared__ float s[256];
    int p = blockIdx.x * 256 + threadIdx.x;    // NN*128
    int i = p >> 7;
    int c4 = (p & 127) * 4;
    int c0 = chunkoffs[i], c1 = chunkoffs[i + 1];
    float4 acc = make_float4(0.f, 0.f, 0.f, 0.f);
    for (int c = c0; c < c1; ++c) {
        float4 v = *reinterpret_cast<const float4*>(&partial[(size_t)c * HIDN + c4]);
        acc.x += v.x; acc.y += v.y; acc.z += v.z; acc.w += v.w;
    }
    float dv = dvv[i];
    float4 wv = *reinterpret_cast<const float4*>(&wbar[c4]);
    float val = fmaxf(acc.x * dv, 0.f) * wv.x + fmaxf(acc.y * dv, 0.f) * wv.y +
                fmaxf(acc.z * dv, 0.f) * wv.z + fmaxf(acc.w * dv, 0.f) * wv.w;
    int t = threadIdx.x;
    s[t] = val; __syncthreads();
    for (int d = 64; d > 0; d >>= 1) {
        if ((t & 127) < d) s[t] += s[t + d];
        __syncthreads();
    }
    if ((t & 127) == 0) g[i] = s[t] * dv * a[i];
}

// ---------------- final reductions ----------------
__global__ __launch_bounds__(1024) void k_yred(const float* __restrict__ g,
                                               float* __restrict__ ys, int slot) {
    __shared__ float s[1024];
    int t = threadIdx.x;
    s[t] = g[t] + g[t + 1024] + g[t + 2048] + g[t + 3072];
    __syncthreads();
    for (int d = 512; d > 0; d >>= 1) { if (t < d) s[t] += s[t + d]; __syncthreads(); }
    if (t == 0) ys[slot] = s[0];
}

__global__ void k_fin(const float* __restrict__ ys, float* __restrict__ out) {
    float y0 = ys[0] / (float)NN, y1 = ys[1] / (float)NN;
    out[0] = 1.0f / (1.0f + expf(-(y0 - y1)));
    out[1] = y0;
    out[2] = y1;
}

// ---------------- launch ----------------
extern "C" void kernel_launch(void* const* d_in, const int* in_sizes, int n_in,
                              void* d_out, int out_size, void* d_ws, size_t ws_size,
                              hipStream_t stream) {
    const float* fts[2] = { (const float*)d_in[0], (const float*)d_in[1] };
    const float* W1 = (const float*)d_in[2];
    const float* W2 = (const float*)d_in[3];
    float* out = (float*)d_out;

    char* p = (char*)d_ws;
    auto alloc = [&](size_t b) { char* r = p; p += (b + 255) & ~(size_t)255; return r; };
    float* G    = (float*)alloc((size_t)NN * NN * 4);        // 64 MB; reused as chunk-partial buffer
    float* nrm  = (float*)alloc((size_t)NN * 4);
    int*   idx  = (int*)  alloc((size_t)NN * 16 * 4);
    int*   Dv   = (int*)  alloc((size_t)NN * 4);
    float* dvv  = (float*)alloc((size_t)NN * 4);
    int*   offs = (int*)  alloc((size_t)(NN + 1) * 4);
    int*   cur  = (int*)  alloc((size_t)NN * 4);
    int*   coffs= (int*)  alloc((size_t)(NN + 1) * 4);
    int*   nch  = (int*)  alloc(4);
    int*   tnode= (int*)  alloc((size_t)MAXCH * 4);
    int*   adj  = (int*)  alloc((size_t)NN * KTOT * 4);
    ushort_t* t1b = (ushort_t*)alloc((size_t)NN * HIDN * 2); // bf16 dv-scaled X@W1
    ushort_t* m   = (ushort_t*)alloc((size_t)NE * HIDN * 2); // bf16 edge means (12.6 MB)
    ushort_t* Xh  = (ushort_t*)alloc((size_t)NN * CC * 2);
    ushort_t* Xl  = (ushort_t*)alloc((size_t)NN * CC * 2);
    ushort_t* W1Th = (ushort_t*)alloc((size_t)HIDN * CC * 2);
    ushort_t* W1Tl = (ushort_t*)alloc((size_t)HIDN * CC * 2);
    float* wbar = (float*)alloc((size_t)HIDN * 4);
    float* ze   = (float*)alloc((size_t)NE * 4);
    float* a    = (float*)alloc((size_t)NN * 4);
    float* g    = (float*)alloc((size_t)NN * 4);
    float* ys   = (float*)alloc(2 * 4);

    float* partial = G;   // chunk partials alias G (free after k_topk); 23.6 MB

    k_wt<<<dim3(HIDN / 32, CC / 32), 256, 0, stream>>>(W1, W1Th, W1Tl);
    k_w2bar<<<HIDN / 256, 256, 0, stream>>>(W2, wbar);

    for (int s = 0; s < 2; ++s) {
        const float* X = fts[s];
        k_rownorm<<<NN, 256, 0, stream>>>(X, nrm);
        k_split<<<NN * CC / 4 / 256, 256, 0, stream>>>(X, Xh, Xl);
        k_mm<true, false, false><<<528, 256, 0, stream>>>(Xh, Xl, Xh, Xl, nullptr, G, nullptr, NN);
        k_topk<<<NN, 256, 0, stream>>>(G, nrm, idx);
        hipMemsetAsync(Dv, 0, NN * 4, stream);
        k_count<<<NN * KTOT / 256, 256, 0, stream>>>(idx, Dv);
        k_dv<<<NN / 256, 256, 0, stream>>>(Dv, dvv);
        k_scan<<<1, 1024, 0, stream>>>(Dv, offs, cur, coffs, nch);
        k_fill<<<NN * KTOT / 256, 256, 0, stream>>>(idx, cur, adj);
        k_tasks<<<NN / 256, 256, 0, stream>>>(coffs, tnode);
        k_ze<<<NE / 256, 256, 0, stream>>>(idx, dvv, ze);
        hipMemsetAsync(a, 0, NN * 4, stream);
        k_ascat<<<NN * KTOT / 256, 256, 0, stream>>>(idx, ze, a);
        // conv1: t1b = bf16(dv * (X @ W1)); m (3 k-blocks, bf16); chunked gather
        k_mm<false, true, true><<<dim3(HIDN / 128, NN / 128), 256, 0, stream>>>(Xh, Xl, W1Th, W1Tl, dvv, nullptr, t1b, HIDN);
        k_edge3<<<NN * 64 / 256, 256, 0, stream>>>(idx, t1b, m);
        k_chunk<<<(MAXCH + 3) / 4, 256, 0, stream>>>(offs, coffs, tnode, nch, adj, m, partial);
        // layer-2 collapsed: g[i] = a_i * (relu(u1_i) . wbar); y = sum(g)/N
        k_comb2<<<NN * 128 / 256, 256, 0, stream>>>(coffs, dvv, a, wbar, partial, g);
        k_yred<<<1, 1024, 0, stream>>>(g, ys, s);
    }
    k_fin<<<1, 1, 0, stream>>>(ys, out);
}